// Round 1
// baseline (3006.993 us; speedup 1.0000x reference)
//
#include <hip/hip_runtime.h>

// ---------------------------------------------------------------------------
// GCN forward: 2x (GEMM -> normalized adjacency aggregate -> bias+ReLU)
//              -> per-graph mean pool -> 2-layer MLP head -> sigmoid
// N=50000 nodes, E=800000 edges, D=HIDDEN=128, G=64 graphs.
// Round 0: correctness-first. Edge aggregation via f32 atomics (known hot
// spot; CSR-gather planned once counters confirm).
// ---------------------------------------------------------------------------

__global__ __launch_bounds__(256) void k_init(float* __restrict__ deg,
                                              float* __restrict__ sums,
                                              float* __restrict__ cnt, int n) {
    int i = blockIdx.x * 256 + threadIdx.x;
    if (i < n) deg[i] = 1.0f;          // self-loop contributes 1 to in-degree
    if (i < 64 * 128) sums[i] = 0.0f;  // pooled sums
    if (i < 64) cnt[i] = 0.0f;         // pooled counts
}

__global__ __launch_bounds__(256) void k_deg(const int* __restrict__ dst,
                                             float* __restrict__ deg, int ne) {
    int e = blockIdx.x * 256 + threadIdx.x;
    if (e < ne) atomicAdd(&deg[dst[e]], 1.0f);
}

__global__ __launch_bounds__(256) void k_dinv(const float* __restrict__ deg,
                                              float* __restrict__ dinv, int n) {
    int i = blockIdx.x * 256 + threadIdx.x;
    if (i < n) dinv[i] = rsqrtf(deg[i]);  // deg >= 1 always (self-loops)
}

// Y[n_rows x 128] = X[n_rows x 128] @ W[128 x 128], f32.
// Block: 256 threads = 32 col-groups (4 cols each) x 8 row-slots; 64 rows/block.
// W (64KB) + X tile (32KB) in LDS. float4 throughout.
__global__ __launch_bounds__(256) void k_gemm128(const float* __restrict__ X,
                                                 const float* __restrict__ W,
                                                 float* __restrict__ Y,
                                                 int n_rows) {
    __shared__ float4 sW[128 * 32];  // W[k][c4] row-major, float4 view
    __shared__ float4 sX[64 * 32];   // X tile, float4 view
    int tid = threadIdx.x;

    const float4* W4 = (const float4*)W;
    for (int i = tid; i < 128 * 32; i += 256) sW[i] = W4[i];

    int row0 = blockIdx.x * 64;
    int nrows = min(64, n_rows - row0);
    const float4* X4 = (const float4*)(X + (size_t)row0 * 128);
    for (int i = tid; i < nrows * 32; i += 256) sX[i] = X4[i];
    // zero the tail rows so tail-block math stays finite (results unused)
    for (int i = nrows * 32 + tid; i < 64 * 32; i += 256)
        sX[i] = make_float4(0.f, 0.f, 0.f, 0.f);
    __syncthreads();

    int c = tid & 31;   // column group: cols 4c..4c+3
    int rs = tid >> 5;  // row slot 0..7

    float4 acc[8];
#pragma unroll
    for (int j = 0; j < 8; ++j) acc[j] = make_float4(0.f, 0.f, 0.f, 0.f);

    for (int k4 = 0; k4 < 32; ++k4) {
        float4 w0 = sW[(4 * k4 + 0) * 32 + c];
        float4 w1 = sW[(4 * k4 + 1) * 32 + c];
        float4 w2 = sW[(4 * k4 + 2) * 32 + c];
        float4 w3 = sW[(4 * k4 + 3) * 32 + c];
#pragma unroll
        for (int j = 0; j < 8; ++j) {
            float4 xv = sX[(rs + 8 * j) * 32 + k4];
            acc[j].x += xv.x * w0.x + xv.y * w1.x + xv.z * w2.x + xv.w * w3.x;
            acc[j].y += xv.x * w0.y + xv.y * w1.y + xv.z * w2.y + xv.w * w3.y;
            acc[j].z += xv.x * w0.z + xv.y * w1.z + xv.z * w2.z + xv.w * w3.z;
            acc[j].w += xv.x * w0.w + xv.y * w1.w + xv.z * w2.w + xv.w * w3.w;
        }
    }

    float4* Y4 = (float4*)(Y + (size_t)row0 * 128);
#pragma unroll
    for (int j = 0; j < 8; ++j) {
        int r = rs + 8 * j;
        if (r < nrows) Y4[r * 32 + c] = acc[j];
    }
}

// out[i][:] = h[i][:] * dinv[i]^2  (self-loop term; also initializes out)
__global__ __launch_bounds__(256) void k_selfloop(const float* __restrict__ h,
                                                  const float* __restrict__ dinv,
                                                  float* __restrict__ out,
                                                  int n) {
    int idx = blockIdx.x * 256 + threadIdx.x;  // over n*32 float4s
    if (idx >= n * 32) return;
    int i = idx >> 5;
    float di = dinv[i];
    float w = di * di;
    float4 v = ((const float4*)h)[idx];
    v.x *= w; v.y *= w; v.z *= w; v.w *= w;
    ((float4*)out)[idx] = v;
}

// out[dst[e]][:] += h[src[e]][:] * dinv[src]*dinv[dst]; 32 threads/edge.
__global__ __launch_bounds__(256) void k_scatter(const float* __restrict__ h,
                                                 const float* __restrict__ dinv,
                                                 const int* __restrict__ src,
                                                 const int* __restrict__ dst,
                                                 float* __restrict__ out,
                                                 int ne) {
    int t = blockIdx.x * 256 + threadIdx.x;
    int e = t >> 5;
    if (e >= ne) return;
    int lane = t & 31;
    int s = src[e];
    int d = dst[e];
    float w = dinv[s] * dinv[d];
    float4 v = ((const float4*)(h + (size_t)s * 128))[lane];
    float* op = out + (size_t)d * 128 + lane * 4;
    atomicAdd(op + 0, v.x * w);
    atomicAdd(op + 1, v.y * w);
    atomicAdd(op + 2, v.z * w);
    atomicAdd(op + 3, v.w * w);
}

// h[i][:] = relu(h[i][:] + b[:]) in place
__global__ __launch_bounds__(256) void k_bias_relu(float* __restrict__ h,
                                                   const float* __restrict__ b,
                                                   int n) {
    int idx = blockIdx.x * 256 + threadIdx.x;  // over n*32 float4s
    if (idx >= n * 32) return;
    float4 bv = ((const float4*)b)[idx & 31];
    float4 v = ((float4*)h)[idx];
    v.x = fmaxf(v.x + bv.x, 0.f);
    v.y = fmaxf(v.y + bv.y, 0.f);
    v.z = fmaxf(v.z + bv.z, 0.f);
    v.w = fmaxf(v.w + bv.w, 0.f);
    ((float4*)h)[idx] = v;
}

// Segmented mean-pool prep: batch is sorted; per-block running-sum with
// flush-on-graph-change => few atomics total.
#define POOL_CHUNK 256
__global__ __launch_bounds__(128) void k_pool(const float* __restrict__ h,
                                              const int* __restrict__ batch,
                                              float* __restrict__ sums,
                                              float* __restrict__ cnt, int n) {
    int d = threadIdx.x;  // 0..127
    int c0 = blockIdx.x * POOL_CHUNK;
    if (c0 >= n) return;
    int c1 = min(c0 + POOL_CHUNK, n);
    float acc = 0.f;
    float cc = 0.f;
    int g_cur = batch[c0];
    for (int i = c0; i < c1; ++i) {
        int g = batch[i];
        if (g != g_cur) {
            atomicAdd(&sums[g_cur * 128 + d], acc);
            if (d == 0) atomicAdd(&cnt[g_cur], cc);
            acc = 0.f; cc = 0.f; g_cur = g;
        }
        acc += h[(size_t)i * 128 + d];
        cc += 1.f;
    }
    atomicAdd(&sums[g_cur * 128 + d], acc);
    if (d == 0) atomicAdd(&cnt[g_cur], cc);
}

// pooled = sums/cnt; z = relu(pooled@Wh1+bh1); out = sigmoid(z@Wh2+bh2)
__global__ __launch_bounds__(128) void k_head(const float* __restrict__ sums,
                                              const float* __restrict__ cnt,
                                              const float* __restrict__ Wh1,
                                              const float* __restrict__ bh1,
                                              const float* __restrict__ Wh2,
                                              const float* __restrict__ bh2,
                                              float* __restrict__ out, int ng) {
    __shared__ float sp[64 * 128];
    __shared__ float sz[64 * 128];
    int d = threadIdx.x;
    for (int g = 0; g < ng; ++g) {
        float c = fmaxf(cnt[g], 1.0f);
        sp[g * 128 + d] = sums[g * 128 + d] / c;
    }
    __syncthreads();
    for (int g = 0; g < ng; ++g) {
        float acc = bh1[d];
        for (int k = 0; k < 128; ++k) acc += sp[g * 128 + k] * Wh1[k * 128 + d];
        sz[g * 128 + d] = fmaxf(acc, 0.f);
    }
    __syncthreads();
    if (d < ng) {
        float acc = bh2[0];
        for (int k = 0; k < 128; ++k) acc += sz[d * 128 + k] * Wh2[k];
        out[d] = 1.f / (1.f + expf(-acc));
    }
}

extern "C" void kernel_launch(void* const* d_in, const int* in_sizes, int n_in,
                              void* d_out, int out_size, void* d_ws,
                              size_t ws_size, hipStream_t stream) {
    const float* x   = (const float*)d_in[0];
    const int*  ei   = (const int*)d_in[1];
    const int*  batch= (const int*)d_in[2];
    const float* W1  = (const float*)d_in[3];
    const float* b1  = (const float*)d_in[4];
    const float* W2  = (const float*)d_in[5];
    const float* b2  = (const float*)d_in[6];
    const float* Wh1 = (const float*)d_in[7];
    const float* bh1 = (const float*)d_in[8];
    const float* Wh2 = (const float*)d_in[9];
    const float* bh2 = (const float*)d_in[10];
    float* out = (float*)d_out;

    const int n  = in_sizes[0] / 128;  // 50000
    const int ne = in_sizes[1] / 2;    // 800000
    const int ng = out_size;           // 64
    const int* src = ei;
    const int* dst = ei + ne;

    float* ws = (float*)d_ws;
    float* deg  = ws;
    float* dinv = ws + n;
    size_t off = (((size_t)2 * n) + 3) & ~(size_t)3;  // 16B-align float4 views
    float* buf0 = ws + off;
    float* buf1 = buf0 + (size_t)n * 128;
    float* sums = buf1 + (size_t)n * 128;
    float* cnt  = sums + 64 * 128;

    int nb_n = (n + 255) / 256;
    int nb_e = (ne + 255) / 256;
    int nb_v = (n * 32 + 255) / 256;
    int nb_s = (int)(((size_t)ne * 32 + 255) / 256);
    int nb_g = (n + 63) / 64;
    int nb_p = (n + POOL_CHUNK - 1) / POOL_CHUNK;

    // degree + normalization (shared by both convs)
    k_init<<<nb_n, 256, 0, stream>>>(deg, sums, cnt, n);
    k_deg<<<nb_e, 256, 0, stream>>>(dst, deg, ne);
    k_dinv<<<nb_n, 256, 0, stream>>>(deg, dinv, n);

    // conv1
    k_gemm128<<<nb_g, 256, 0, stream>>>(x, W1, buf0, n);
    k_selfloop<<<nb_v, 256, 0, stream>>>(buf0, dinv, buf1, n);
    k_scatter<<<nb_s, 256, 0, stream>>>(buf0, dinv, src, dst, buf1, ne);
    k_bias_relu<<<nb_v, 256, 0, stream>>>(buf1, b1, n);

    // conv2
    k_gemm128<<<nb_g, 256, 0, stream>>>(buf1, W2, buf0, n);
    k_selfloop<<<nb_v, 256, 0, stream>>>(buf0, dinv, buf1, n);
    k_scatter<<<nb_s, 256, 0, stream>>>(buf0, dinv, src, dst, buf1, ne);
    k_bias_relu<<<nb_v, 256, 0, stream>>>(buf1, b2, n);

    // pool + head
    k_pool<<<nb_p, 128, 0, stream>>>(buf1, batch, sums, cnt, n);
    k_head<<<1, 128, 0, stream>>>(sums, cnt, Wh1, bh1, Wh2, bh2, out, ng);
}

// Round 4
// 651.986 us; speedup vs baseline: 4.6121x; 4.6121x over previous
//
#include <hip/hip_runtime.h>

// ---------------------------------------------------------------------------
// GCN forward, round 1 (2nd resubmit; two consecutive container failures):
// atomic scatter -> per-launch CSR build + pure gather.
// R0 counters: k_scatter WRITE_SIZE=1.6GB (atomics write through to HBM),
// 2x1320us = 88% of total. CSR gather reads h (25.6MB, cache-resident) and
// writes each output row exactly once.
// ---------------------------------------------------------------------------

__global__ __launch_bounds__(256) void k_zero(int* __restrict__ count,
                                              float* __restrict__ sums,
                                              float* __restrict__ cnt, int n) {
    int i = blockIdx.x * 256 + threadIdx.x;
    if (i < n) count[i] = 0;
    if (i < 64 * 128) sums[i] = 0.0f;
    if (i < 64) cnt[i] = 0.0f;
}

__global__ __launch_bounds__(256) void k_count(const int* __restrict__ dst,
                                               int* __restrict__ count, int ne) {
    int e = blockIdx.x * 256 + threadIdx.x;
    if (e < ne) atomicAdd(&count[dst[e]], 1);
}

// Single-block exclusive scan over count[0..n) -> row_start; also emits
// dinv[i] = rsqrt(count[i]+1) (self-loop) and re-zeros count for reuse as
// the fill cursor. n <= 1024*CH.
__global__ __launch_bounds__(1024) void k_scan(int* __restrict__ count,
                                               int* __restrict__ row_start,
                                               float* __restrict__ dinv,
                                               int n, int ne) {
    __shared__ int ps[1024];
    const int CH = (n + 1023) / 1024;
    int tid = threadIdx.x;
    int c0 = tid * CH, c1 = min(c0 + CH, n);
    int s = 0;
    for (int i = c0; i < c1; ++i) s += count[i];
    ps[tid] = s;
    __syncthreads();
    for (int off = 1; off < 1024; off <<= 1) {
        int v = (tid >= off) ? ps[tid - off] : 0;
        __syncthreads();
        ps[tid] += v;
        __syncthreads();
    }
    int run = ps[tid] - s;  // exclusive prefix of this thread's chunk
    for (int i = c0; i < c1; ++i) {
        row_start[i] = run;
        int c = count[i];
        run += c;
        dinv[i] = rsqrtf((float)c + 1.0f);
        count[i] = 0;  // becomes the fill cursor
    }
    if (tid == 1023) row_start[n] = ne;
}

__global__ __launch_bounds__(256) void k_fill(const int* __restrict__ src,
                                              const int* __restrict__ dst,
                                              const int* __restrict__ row_start,
                                              int* __restrict__ cursor,
                                              int* __restrict__ csr, int ne) {
    int e = blockIdx.x * 256 + threadIdx.x;
    if (e >= ne) return;
    int d = dst[e];
    int pos = atomicAdd(&cursor[d], 1);
    csr[row_start[d] + pos] = src[e];
}

// Y[n_rows x 128] = X[n_rows x 128] @ W[128 x 128], f32.
// 256 threads = 32 col-groups (4 cols) x 8 row-slots; 64 rows/block.
__global__ __launch_bounds__(256) void k_gemm128(const float* __restrict__ X,
                                                 const float* __restrict__ W,
                                                 float* __restrict__ Y,
                                                 int n_rows) {
    __shared__ float4 sW[128 * 32];
    __shared__ float4 sX[64 * 32];
    int tid = threadIdx.x;

    const float4* W4 = (const float4*)W;
    for (int i = tid; i < 128 * 32; i += 256) sW[i] = W4[i];

    int row0 = blockIdx.x * 64;
    int nrows = min(64, n_rows - row0);
    const float4* X4 = (const float4*)(X + (size_t)row0 * 128);
    for (int i = tid; i < nrows * 32; i += 256) sX[i] = X4[i];
    for (int i = nrows * 32 + tid; i < 64 * 32; i += 256)
        sX[i] = make_float4(0.f, 0.f, 0.f, 0.f);
    __syncthreads();

    int c = tid & 31;
    int rs = tid >> 5;

    float4 acc[8];
#pragma unroll
    for (int j = 0; j < 8; ++j) acc[j] = make_float4(0.f, 0.f, 0.f, 0.f);

    for (int k4 = 0; k4 < 32; ++k4) {
        float4 w0 = sW[(4 * k4 + 0) * 32 + c];
        float4 w1 = sW[(4 * k4 + 1) * 32 + c];
        float4 w2 = sW[(4 * k4 + 2) * 32 + c];
        float4 w3 = sW[(4 * k4 + 3) * 32 + c];
#pragma unroll
        for (int j = 0; j < 8; ++j) {
            float4 xv = sX[(rs + 8 * j) * 32 + k4];
            acc[j].x += xv.x * w0.x + xv.y * w1.x + xv.z * w2.x + xv.w * w3.x;
            acc[j].y += xv.x * w0.y + xv.y * w1.y + xv.z * w2.y + xv.w * w3.y;
            acc[j].z += xv.x * w0.z + xv.y * w1.z + xv.z * w2.z + xv.w * w3.z;
            acc[j].w += xv.x * w0.w + xv.y * w1.w + xv.z * w2.w + xv.w * w3.w;
        }
    }

    float4* Y4 = (float4*)(Y + (size_t)row0 * 128);
#pragma unroll
    for (int j = 0; j < 8; ++j) {
        int r = rs + 8 * j;
        if (r < nrows) Y4[r * 32 + c] = acc[j];
    }
}

// out[d][:] = relu( sum_{e: dst==d} h[src_e][:] * dinv[src]*dinv[d]
//                   + h[d][:]*dinv[d]^2 + bias ).
// One wave (64 lanes x float2) per node; edge srcs preloaded per-lane and
// broadcast via shfl (covers deg<=64; loop fallback beyond).
__global__ __launch_bounds__(256) void k_agg(const float* __restrict__ h,
                                             const float* __restrict__ dinv,
                                             const int* __restrict__ csr,
                                             const int* __restrict__ row_start,
                                             const float* __restrict__ bias,
                                             float* __restrict__ out, int n) {
    int node = blockIdx.x * 4 + (threadIdx.x >> 6);
    if (node >= n) return;
    int lane = threadIdx.x & 63;
    const float2* h2 = (const float2*)h;

    float di = dinv[node];
    float2 hv = h2[(size_t)node * 64 + lane];
    float ax = hv.x * di * di;
    float ay = hv.y * di * di;

    int beg = row_start[node];
    int end = row_start[node + 1];
    int deg = end - beg;

    int mysrc = (lane < deg) ? csr[beg + lane] : 0;
    float myw = (lane < deg) ? dinv[mysrc] : 0.0f;

    int m = min(deg, 64);
    for (int e = 0; e < m; ++e) {
        int s = __shfl(mysrc, e);
        float w = __shfl(myw, e) * di;
        float2 v = h2[(size_t)s * 64 + lane];
        ax += v.x * w;
        ay += v.y * w;
    }
    for (int j = beg + 64; j < end; ++j) {  // rare: deg > 64
        int s = csr[j];
        float w = dinv[s] * di;
        float2 v = h2[(size_t)s * 64 + lane];
        ax += v.x * w;
        ay += v.y * w;
    }

    float2 bv = ((const float2*)bias)[lane];
    float2 o;
    o.x = fmaxf(ax + bv.x, 0.0f);
    o.y = fmaxf(ay + bv.y, 0.0f);
    ((float2*)out)[(size_t)node * 64 + lane] = o;
}

// Segmented mean-pool: batch sorted; per-block running sum, flush on change.
#define POOL_CHUNK 256
__global__ __launch_bounds__(128) void k_pool(const float* __restrict__ h,
                                              const int* __restrict__ batch,
                                              float* __restrict__ sums,
                                              float* __restrict__ cnt, int n) {
    int d = threadIdx.x;
    int c0 = blockIdx.x * POOL_CHUNK;
    if (c0 >= n) return;
    int c1 = min(c0 + POOL_CHUNK, n);
    float acc = 0.f, cc = 0.f;
    int g_cur = batch[c0];
    for (int i = c0; i < c1; ++i) {
        int g = batch[i];
        if (g != g_cur) {
            atomicAdd(&sums[g_cur * 128 + d], acc);
            if (d == 0) atomicAdd(&cnt[g_cur], cc);
            acc = 0.f; cc = 0.f; g_cur = g;
        }
        acc += h[(size_t)i * 128 + d];
        cc += 1.f;
    }
    atomicAdd(&sums[g_cur * 128 + d], acc);
    if (d == 0) atomicAdd(&cnt[g_cur], cc);
}

__global__ __launch_bounds__(128) void k_head(const float* __restrict__ sums,
                                              const float* __restrict__ cnt,
                                              const float* __restrict__ Wh1,
                                              const float* __restrict__ bh1,
                                              const float* __restrict__ Wh2,
                                              const float* __restrict__ bh2,
                                              float* __restrict__ out, int ng) {
    __shared__ float sp[64 * 128];
    __shared__ float sz[64 * 128];
    int d = threadIdx.x;
    for (int g = 0; g < ng; ++g) {
        float c = fmaxf(cnt[g], 1.0f);
        sp[g * 128 + d] = sums[g * 128 + d] / c;
    }
    __syncthreads();
    for (int g = 0; g < ng; ++g) {
        float acc = bh1[d];
        for (int k = 0; k < 128; ++k) acc += sp[g * 128 + k] * Wh1[k * 128 + d];
        sz[g * 128 + d] = fmaxf(acc, 0.f);
    }
    __syncthreads();
    if (d < ng) {
        float acc = bh2[0];
        for (int k = 0; k < 128; ++k) acc += sz[d * 128 + k] * Wh2[k];
        out[d] = 1.f / (1.f + expf(-acc));
    }
}

extern "C" void kernel_launch(void* const* d_in, const int* in_sizes, int n_in,
                              void* d_out, int out_size, void* d_ws,
                              size_t ws_size, hipStream_t stream) {
    const float* x    = (const float*)d_in[0];
    const int*   ei   = (const int*)d_in[1];
    const int*   batch= (const int*)d_in[2];
    const float* W1   = (const float*)d_in[3];
    const float* b1   = (const float*)d_in[4];
    const float* W2   = (const float*)d_in[5];
    const float* b2   = (const float*)d_in[6];
    const float* Wh1  = (const float*)d_in[7];
    const float* bh1  = (const float*)d_in[8];
    const float* Wh2  = (const float*)d_in[9];
    const float* bh2  = (const float*)d_in[10];
    float* out = (float*)d_out;

    const int n  = in_sizes[0] / 128;  // 50000
    const int ne = in_sizes[1] / 2;    // 800000
    const int ng = out_size;           // 64
    const int* src = ei;
    const int* dst = ei + ne;

    char* p = (char*)d_ws;
    int* count     = (int*)p;  p += (size_t)n * 4;
    int* row_start = (int*)p;  p += (size_t)(n + 1) * 4;
    int* csr       = (int*)p;  p += (size_t)ne * 4;
    float* dinv    = (float*)p; p += (size_t)n * 4;
    p = (char*)(((uintptr_t)p + 15) & ~(uintptr_t)15);
    float* buf0 = (float*)p;   p += (size_t)n * 128 * 4;
    float* buf1 = (float*)p;   p += (size_t)n * 128 * 4;
    float* sums = (float*)p;   p += (size_t)64 * 128 * 4;
    float* cnt  = (float*)p;

    int nb_n = (n + 255) / 256;
    int nb_e = (ne + 255) / 256;
    int nb_g = (n + 63) / 64;
    int nb_a = (n + 3) / 4;
    int nb_p = (n + POOL_CHUNK - 1) / POOL_CHUNK;

    // CSR build + norms
    k_zero<<<nb_n, 256, 0, stream>>>(count, sums, cnt, n);
    k_count<<<nb_e, 256, 0, stream>>>(dst, count, ne);
    k_scan<<<1, 1024, 0, stream>>>(count, row_start, dinv, n, ne);
    k_fill<<<nb_e, 256, 0, stream>>>(src, dst, row_start, count, csr, ne);

    // conv1
    k_gemm128<<<nb_g, 256, 0, stream>>>(x, W1, buf0, n);
    k_agg<<<nb_a, 256, 0, stream>>>(buf0, dinv, csr, row_start, b1, buf1, n);

    // conv2
    k_gemm128<<<nb_g, 256, 0, stream>>>(buf1, W2, buf0, n);
    k_agg<<<nb_a, 256, 0, stream>>>(buf0, dinv, csr, row_start, b2, buf1, n);

    // pool + head
    k_pool<<<nb_p, 128, 0, stream>>>(buf1, batch, sums, cnt, n);
    k_head<<<1, 128, 0, stream>>>(sums, cnt, Wh1, bh1, Wh2, bh2, out, ng);
}

// Round 5
// 383.038 us; speedup vs baseline: 7.8504x; 1.7021x over previous
//
#include <hip/hip_runtime.h>

// ---------------------------------------------------------------------------
// GCN forward, round 2: parallelize the serial stragglers.
// R1 counters: k_scan (single-block) = 134us @ 0.14% occupancy = 20% of total.
// -> 3-kernel hierarchical scan. Also k_pool chunk 256->64, k_head 1 block ->
// 64 blocks (one per graph).
// ---------------------------------------------------------------------------

__global__ __launch_bounds__(256) void k_zero(int* __restrict__ count,
                                              float* __restrict__ sums,
                                              float* __restrict__ cnt, int n) {
    int i = blockIdx.x * 256 + threadIdx.x;
    if (i < n) count[i] = 0;
    if (i < 64 * 128) sums[i] = 0.0f;
    if (i < 64) cnt[i] = 0.0f;
}

__global__ __launch_bounds__(256) void k_count(const int* __restrict__ dst,
                                               int* __restrict__ count, int ne) {
    int e = blockIdx.x * 256 + threadIdx.x;
    if (e < ne) atomicAdd(&count[dst[e]], 1);
}

// Pass 1: block-local exclusive scan of count -> row_start (pre-offset),
// block total -> blk_sums[blockIdx].
__global__ __launch_bounds__(256) void k_scan1(const int* __restrict__ count,
                                               int* __restrict__ row_start,
                                               int* __restrict__ blk_sums,
                                               int n) {
    __shared__ int ps[256];
    int tid = threadIdx.x;
    int i = blockIdx.x * 256 + tid;
    int c = (i < n) ? count[i] : 0;
    ps[tid] = c;
    __syncthreads();
    for (int off = 1; off < 256; off <<= 1) {
        int v = (tid >= off) ? ps[tid - off] : 0;
        __syncthreads();
        ps[tid] += v;
        __syncthreads();
    }
    if (i < n) row_start[i] = ps[tid] - c;  // exclusive
    if (tid == 255) blk_sums[blockIdx.x] = ps[255];
}

// Pass 2: single-block exclusive scan of blk_sums[0..nblk).
__global__ __launch_bounds__(256) void k_scan2(int* __restrict__ blk_sums,
                                               int nblk) {
    __shared__ int ps[256];
    int tid = threadIdx.x;
    int c = (tid < nblk) ? blk_sums[tid] : 0;
    ps[tid] = c;
    __syncthreads();
    for (int off = 1; off < 256; off <<= 1) {
        int v = (tid >= off) ? ps[tid - off] : 0;
        __syncthreads();
        ps[tid] += v;
        __syncthreads();
    }
    if (tid < nblk) blk_sums[tid] = ps[tid] - c;  // exclusive
}

// Pass 3: add block offset; emit dinv; reset count as fill cursor.
__global__ __launch_bounds__(256) void k_scan3(int* __restrict__ count,
                                               int* __restrict__ row_start,
                                               const int* __restrict__ blk_sums,
                                               float* __restrict__ dinv,
                                               int n, int ne) {
    int i = blockIdx.x * 256 + threadIdx.x;
    if (i == 0) row_start[n] = ne;
    if (i >= n) return;
    row_start[i] += blk_sums[blockIdx.x];
    int c = count[i];
    dinv[i] = rsqrtf((float)c + 1.0f);
    count[i] = 0;
}

__global__ __launch_bounds__(256) void k_fill(const int* __restrict__ src,
                                              const int* __restrict__ dst,
                                              const int* __restrict__ row_start,
                                              int* __restrict__ cursor,
                                              int* __restrict__ csr, int ne) {
    int e = blockIdx.x * 256 + threadIdx.x;
    if (e >= ne) return;
    int d = dst[e];
    int pos = atomicAdd(&cursor[d], 1);
    csr[row_start[d] + pos] = src[e];
}

// Y[n_rows x 128] = X[n_rows x 128] @ W[128 x 128], f32.
// 256 threads = 32 col-groups (4 cols) x 8 row-slots; 64 rows/block.
__global__ __launch_bounds__(256) void k_gemm128(const float* __restrict__ X,
                                                 const float* __restrict__ W,
                                                 float* __restrict__ Y,
                                                 int n_rows) {
    __shared__ float4 sW[128 * 32];
    __shared__ float4 sX[64 * 32];
    int tid = threadIdx.x;

    const float4* W4 = (const float4*)W;
    for (int i = tid; i < 128 * 32; i += 256) sW[i] = W4[i];

    int row0 = blockIdx.x * 64;
    int nrows = min(64, n_rows - row0);
    const float4* X4 = (const float4*)(X + (size_t)row0 * 128);
    for (int i = tid; i < nrows * 32; i += 256) sX[i] = X4[i];
    for (int i = nrows * 32 + tid; i < 64 * 32; i += 256)
        sX[i] = make_float4(0.f, 0.f, 0.f, 0.f);
    __syncthreads();

    int c = tid & 31;
    int rs = tid >> 5;

    float4 acc[8];
#pragma unroll
    for (int j = 0; j < 8; ++j) acc[j] = make_float4(0.f, 0.f, 0.f, 0.f);

    for (int k4 = 0; k4 < 32; ++k4) {
        float4 w0 = sW[(4 * k4 + 0) * 32 + c];
        float4 w1 = sW[(4 * k4 + 1) * 32 + c];
        float4 w2 = sW[(4 * k4 + 2) * 32 + c];
        float4 w3 = sW[(4 * k4 + 3) * 32 + c];
#pragma unroll
        for (int j = 0; j < 8; ++j) {
            float4 xv = sX[(rs + 8 * j) * 32 + k4];
            acc[j].x += xv.x * w0.x + xv.y * w1.x + xv.z * w2.x + xv.w * w3.x;
            acc[j].y += xv.x * w0.y + xv.y * w1.y + xv.z * w2.y + xv.w * w3.y;
            acc[j].z += xv.x * w0.z + xv.y * w1.z + xv.z * w2.z + xv.w * w3.z;
            acc[j].w += xv.x * w0.w + xv.y * w1.w + xv.z * w2.w + xv.w * w3.w;
        }
    }

    float4* Y4 = (float4*)(Y + (size_t)row0 * 128);
#pragma unroll
    for (int j = 0; j < 8; ++j) {
        int r = rs + 8 * j;
        if (r < nrows) Y4[r * 32 + c] = acc[j];
    }
}

// out[d][:] = relu( sum_{e: dst==d} h[src_e][:] * dinv[src]*dinv[d]
//                   + h[d][:]*dinv[d]^2 + bias ).
// One wave (64 lanes x float2) per node; srcs preloaded per-lane, shfl-bcast.
__global__ __launch_bounds__(256) void k_agg(const float* __restrict__ h,
                                             const float* __restrict__ dinv,
                                             const int* __restrict__ csr,
                                             const int* __restrict__ row_start,
                                             const float* __restrict__ bias,
                                             float* __restrict__ out, int n) {
    int node = blockIdx.x * 4 + (threadIdx.x >> 6);
    if (node >= n) return;
    int lane = threadIdx.x & 63;
    const float2* h2 = (const float2*)h;

    float di = dinv[node];
    float2 hv = h2[(size_t)node * 64 + lane];
    float ax = hv.x * di * di;
    float ay = hv.y * di * di;

    int beg = row_start[node];
    int end = row_start[node + 1];
    int deg = end - beg;

    int mysrc = (lane < deg) ? csr[beg + lane] : 0;
    float myw = (lane < deg) ? dinv[mysrc] : 0.0f;

    int m = min(deg, 64);
    for (int e = 0; e < m; ++e) {
        int s = __shfl(mysrc, e);
        float w = __shfl(myw, e) * di;
        float2 v = h2[(size_t)s * 64 + lane];
        ax += v.x * w;
        ay += v.y * w;
    }
    for (int j = beg + 64; j < end; ++j) {  // rare: deg > 64
        int s = csr[j];
        float w = dinv[s] * di;
        float2 v = h2[(size_t)s * 64 + lane];
        ax += v.x * w;
        ay += v.y * w;
    }

    float2 bv = ((const float2*)bias)[lane];
    float2 o;
    o.x = fmaxf(ax + bv.x, 0.0f);
    o.y = fmaxf(ay + bv.y, 0.0f);
    ((float2*)out)[(size_t)node * 64 + lane] = o;
}

// Segmented mean-pool: batch sorted; per-block running sum, flush on change.
#define POOL_CHUNK 64
__global__ __launch_bounds__(128) void k_pool(const float* __restrict__ h,
                                              const int* __restrict__ batch,
                                              float* __restrict__ sums,
                                              float* __restrict__ cnt, int n) {
    int d = threadIdx.x;
    int c0 = blockIdx.x * POOL_CHUNK;
    if (c0 >= n) return;
    int c1 = min(c0 + POOL_CHUNK, n);
    float acc = 0.f, cc = 0.f;
    int g_cur = batch[c0];
    for (int i = c0; i < c1; ++i) {
        int g = batch[i];
        if (g != g_cur) {
            atomicAdd(&sums[g_cur * 128 + d], acc);
            if (d == 0) atomicAdd(&cnt[g_cur], cc);
            acc = 0.f; cc = 0.f; g_cur = g;
        }
        acc += h[(size_t)i * 128 + d];
        cc += 1.f;
    }
    atomicAdd(&sums[g_cur * 128 + d], acc);
    if (d == 0) atomicAdd(&cnt[g_cur], cc);
}

// One block per graph: pooled mean -> Linear+ReLU -> dot+sigmoid.
__global__ __launch_bounds__(128) void k_head(const float* __restrict__ sums,
                                              const float* __restrict__ cnt,
                                              const float* __restrict__ Wh1,
                                              const float* __restrict__ bh1,
                                              const float* __restrict__ Wh2,
                                              const float* __restrict__ bh2,
                                              float* __restrict__ out) {
    int g = blockIdx.x;
    int d = threadIdx.x;
    __shared__ float sp[128];
    __shared__ float red[128];
    float c = fmaxf(cnt[g], 1.0f);
    sp[d] = sums[g * 128 + d] / c;
    __syncthreads();
    float acc = bh1[d];
    for (int k = 0; k < 128; ++k) acc += sp[k] * Wh1[k * 128 + d];
    float z = fmaxf(acc, 0.f);
    red[d] = z * Wh2[d];
    __syncthreads();
    for (int off = 64; off > 0; off >>= 1) {
        if (d < off) red[d] += red[d + off];
        __syncthreads();
    }
    if (d == 0) out[g] = 1.f / (1.f + expf(-(red[0] + bh2[0])));
}

extern "C" void kernel_launch(void* const* d_in, const int* in_sizes, int n_in,
                              void* d_out, int out_size, void* d_ws,
                              size_t ws_size, hipStream_t stream) {
    const float* x    = (const float*)d_in[0];
    const int*   ei   = (const int*)d_in[1];
    const int*   batch= (const int*)d_in[2];
    const float* W1   = (const float*)d_in[3];
    const float* b1   = (const float*)d_in[4];
    const float* W2   = (const float*)d_in[5];
    const float* b2   = (const float*)d_in[6];
    const float* Wh1  = (const float*)d_in[7];
    const float* bh1  = (const float*)d_in[8];
    const float* Wh2  = (const float*)d_in[9];
    const float* bh2  = (const float*)d_in[10];
    float* out = (float*)d_out;

    const int n  = in_sizes[0] / 128;  // 50000
    const int ne = in_sizes[1] / 2;    // 800000
    const int* src = ei;
    const int* dst = ei + ne;

    char* p = (char*)d_ws;
    int* count     = (int*)p;  p += (size_t)n * 4;
    int* row_start = (int*)p;  p += (size_t)(n + 1) * 4;
    int* csr       = (int*)p;  p += (size_t)ne * 4;
    float* dinv    = (float*)p; p += (size_t)n * 4;
    int* blk_sums  = (int*)p;  p += 256 * 4;
    p = (char*)(((uintptr_t)p + 15) & ~(uintptr_t)15);
    float* buf0 = (float*)p;   p += (size_t)n * 128 * 4;
    float* buf1 = (float*)p;   p += (size_t)n * 128 * 4;
    float* sums = (float*)p;   p += (size_t)64 * 128 * 4;
    float* cnt  = (float*)p;

    int nb_n = (n + 255) / 256;  // 196 (also the scan block count, <=256)
    int nb_e = (ne + 255) / 256;
    int nb_g = (n + 63) / 64;
    int nb_a = (n + 3) / 4;
    int nb_p = (n + POOL_CHUNK - 1) / POOL_CHUNK;

    // CSR build + norms (hierarchical scan)
    k_zero<<<nb_n, 256, 0, stream>>>(count, sums, cnt, n);
    k_count<<<nb_e, 256, 0, stream>>>(dst, count, ne);
    k_scan1<<<nb_n, 256, 0, stream>>>(count, row_start, blk_sums, n);
    k_scan2<<<1, 256, 0, stream>>>(blk_sums, nb_n);
    k_scan3<<<nb_n, 256, 0, stream>>>(count, row_start, blk_sums, dinv, n, ne);
    k_fill<<<nb_e, 256, 0, stream>>>(src, dst, row_start, count, csr, ne);

    // conv1
    k_gemm128<<<nb_g, 256, 0, stream>>>(x, W1, buf0, n);
    k_agg<<<nb_a, 256, 0, stream>>>(buf0, dinv, csr, row_start, b1, buf1, n);

    // conv2
    k_gemm128<<<nb_g, 256, 0, stream>>>(buf1, W2, buf0, n);
    k_agg<<<nb_a, 256, 0, stream>>>(buf0, dinv, csr, row_start, b2, buf1, n);

    // pool + head
    k_pool<<<nb_p, 128, 0, stream>>>(buf1, batch, sums, cnt, n);
    k_head<<<64, 128, 0, stream>>>(sums, cnt, Wh1, bh1, Wh2, bh2, out);
}

// Round 6
// 353.171 us; speedup vs baseline: 8.5143x; 1.0846x over previous
//
#include <hip/hip_runtime.h>

// ---------------------------------------------------------------------------
// GCN forward, round 3: bf16 gather.
// R2 counters: k_agg 2x75.5us, FETCH_SIZE=228MB (gather of 512B f32 rows
// misses 4MB per-XCD L2). -> store h rows in bf16 (GEMM epilogue converts),
// halving gather traffic. Accumulate f32; everything else unchanged.
// ---------------------------------------------------------------------------

__device__ inline unsigned short f2bf(float f) {
    union { float f; unsigned int u; } c; c.f = f;
    unsigned int u = c.u + (0x7fffu + ((c.u >> 16) & 1u));  // RNE
    return (unsigned short)(u >> 16);
}

__global__ __launch_bounds__(256) void k_zero(int* __restrict__ count,
                                              float* __restrict__ sums,
                                              float* __restrict__ cnt, int n) {
    int i = blockIdx.x * 256 + threadIdx.x;
    if (i < n) count[i] = 0;
    if (i < 64 * 128) sums[i] = 0.0f;
    if (i < 64) cnt[i] = 0.0f;
}

__global__ __launch_bounds__(256) void k_count(const int* __restrict__ dst,
                                               int* __restrict__ count, int ne) {
    int e = blockIdx.x * 256 + threadIdx.x;
    if (e < ne) atomicAdd(&count[dst[e]], 1);
}

__global__ __launch_bounds__(256) void k_scan1(const int* __restrict__ count,
                                               int* __restrict__ row_start,
                                               int* __restrict__ blk_sums,
                                               int n) {
    __shared__ int ps[256];
    int tid = threadIdx.x;
    int i = blockIdx.x * 256 + tid;
    int c = (i < n) ? count[i] : 0;
    ps[tid] = c;
    __syncthreads();
    for (int off = 1; off < 256; off <<= 1) {
        int v = (tid >= off) ? ps[tid - off] : 0;
        __syncthreads();
        ps[tid] += v;
        __syncthreads();
    }
    if (i < n) row_start[i] = ps[tid] - c;
    if (tid == 255) blk_sums[blockIdx.x] = ps[255];
}

__global__ __launch_bounds__(256) void k_scan2(int* __restrict__ blk_sums,
                                               int nblk) {
    __shared__ int ps[256];
    int tid = threadIdx.x;
    int c = (tid < nblk) ? blk_sums[tid] : 0;
    ps[tid] = c;
    __syncthreads();
    for (int off = 1; off < 256; off <<= 1) {
        int v = (tid >= off) ? ps[tid - off] : 0;
        __syncthreads();
        ps[tid] += v;
        __syncthreads();
    }
    if (tid < nblk) blk_sums[tid] = ps[tid] - c;
}

__global__ __launch_bounds__(256) void k_scan3(int* __restrict__ count,
                                               int* __restrict__ row_start,
                                               const int* __restrict__ blk_sums,
                                               float* __restrict__ dinv,
                                               int n, int ne) {
    int i = blockIdx.x * 256 + threadIdx.x;
    if (i == 0) row_start[n] = ne;
    if (i >= n) return;
    row_start[i] += blk_sums[blockIdx.x];
    int c = count[i];
    dinv[i] = rsqrtf((float)c + 1.0f);
    count[i] = 0;
}

__global__ __launch_bounds__(256) void k_fill(const int* __restrict__ src,
                                              const int* __restrict__ dst,
                                              const int* __restrict__ row_start,
                                              int* __restrict__ cursor,
                                              int* __restrict__ csr, int ne) {
    int e = blockIdx.x * 256 + threadIdx.x;
    if (e >= ne) return;
    int d = dst[e];
    int pos = atomicAdd(&cursor[d], 1);
    csr[row_start[d] + pos] = src[e];
}

// Y[n_rows x 128](bf16) = X[n_rows x 128](f32) @ W[128 x 128](f32).
// 256 threads = 32 col-groups (4 cols) x 8 row-slots; 64 rows/block.
__global__ __launch_bounds__(256) void k_gemm128(const float* __restrict__ X,
                                                 const float* __restrict__ W,
                                                 unsigned short* __restrict__ Yb,
                                                 int n_rows) {
    __shared__ float4 sW[128 * 32];
    __shared__ float4 sX[64 * 32];
    int tid = threadIdx.x;

    const float4* W4 = (const float4*)W;
    for (int i = tid; i < 128 * 32; i += 256) sW[i] = W4[i];

    int row0 = blockIdx.x * 64;
    int nrows = min(64, n_rows - row0);
    const float4* X4 = (const float4*)(X + (size_t)row0 * 128);
    for (int i = tid; i < nrows * 32; i += 256) sX[i] = X4[i];
    for (int i = nrows * 32 + tid; i < 64 * 32; i += 256)
        sX[i] = make_float4(0.f, 0.f, 0.f, 0.f);
    __syncthreads();

    int c = tid & 31;
    int rs = tid >> 5;

    float4 acc[8];
#pragma unroll
    for (int j = 0; j < 8; ++j) acc[j] = make_float4(0.f, 0.f, 0.f, 0.f);

    for (int k4 = 0; k4 < 32; ++k4) {
        float4 w0 = sW[(4 * k4 + 0) * 32 + c];
        float4 w1 = sW[(4 * k4 + 1) * 32 + c];
        float4 w2 = sW[(4 * k4 + 2) * 32 + c];
        float4 w3 = sW[(4 * k4 + 3) * 32 + c];
#pragma unroll
        for (int j = 0; j < 8; ++j) {
            float4 xv = sX[(rs + 8 * j) * 32 + k4];
            acc[j].x += xv.x * w0.x + xv.y * w1.x + xv.z * w2.x + xv.w * w3.x;
            acc[j].y += xv.x * w0.y + xv.y * w1.y + xv.z * w2.y + xv.w * w3.y;
            acc[j].z += xv.x * w0.z + xv.y * w1.z + xv.z * w2.z + xv.w * w3.z;
            acc[j].w += xv.x * w0.w + xv.y * w1.w + xv.z * w2.w + xv.w * w3.w;
        }
    }

    // epilogue: f32 -> bf16, 4 cols per thread = one ushort4 (8B)
    ushort4* Y4 = (ushort4*)(Yb + (size_t)row0 * 128);
#pragma unroll
    for (int j = 0; j < 8; ++j) {
        int r = rs + 8 * j;
        if (r < nrows) {
            ushort4 o;
            o.x = f2bf(acc[j].x);
            o.y = f2bf(acc[j].y);
            o.z = f2bf(acc[j].z);
            o.w = f2bf(acc[j].w);
            Y4[r * 32 + c] = o;
        }
    }
}

// out[d][:] = relu( sum_{e} h[src_e]*dinv[src]*dinv[d] + h[d]*dinv[d]^2 + b ).
// h is bf16 [n x 128]; one wave per node, lane covers 2 bf16 (one dword).
__global__ __launch_bounds__(256) void k_agg(const unsigned short* __restrict__ h,
                                             const float* __restrict__ dinv,
                                             const int* __restrict__ csr,
                                             const int* __restrict__ row_start,
                                             const float* __restrict__ bias,
                                             float* __restrict__ out, int n) {
    int node = blockIdx.x * 4 + (threadIdx.x >> 6);
    if (node >= n) return;
    int lane = threadIdx.x & 63;
    const unsigned int* h2 = (const unsigned int*)h;  // 2 bf16 per dword

    union { unsigned int u; float f; } cv;
    float di = dinv[node];

    unsigned int hu = h2[(size_t)node * 64 + lane];
    cv.u = hu << 16;            float hx = cv.f;
    cv.u = hu & 0xffff0000u;    float hy = cv.f;
    float ax = hx * di * di;
    float ay = hy * di * di;

    int beg = row_start[node];
    int end = row_start[node + 1];
    int deg = end - beg;

    int mysrc = (lane < deg) ? csr[beg + lane] : 0;
    float myw = (lane < deg) ? dinv[mysrc] : 0.0f;

    int m = min(deg, 64);
    for (int e = 0; e < m; ++e) {
        int s = __shfl(mysrc, e);
        float w = __shfl(myw, e) * di;
        unsigned int u = h2[(size_t)s * 64 + lane];
        cv.u = u << 16;          float vx = cv.f;
        cv.u = u & 0xffff0000u;  float vy = cv.f;
        ax += vx * w;
        ay += vy * w;
    }
    for (int j = beg + 64; j < end; ++j) {  // rare: deg > 64
        int s = csr[j];
        float w = dinv[s] * di;
        unsigned int u = h2[(size_t)s * 64 + lane];
        cv.u = u << 16;          float vx = cv.f;
        cv.u = u & 0xffff0000u;  float vy = cv.f;
        ax += vx * w;
        ay += vy * w;
    }

    float2 bv = ((const float2*)bias)[lane];
    float2 o;
    o.x = fmaxf(ax + bv.x, 0.0f);
    o.y = fmaxf(ay + bv.y, 0.0f);
    ((float2*)out)[(size_t)node * 64 + lane] = o;
}

// Segmented mean-pool: batch sorted; per-block running sum, flush on change.
#define POOL_CHUNK 64
__global__ __launch_bounds__(128) void k_pool(const float* __restrict__ h,
                                              const int* __restrict__ batch,
                                              float* __restrict__ sums,
                                              float* __restrict__ cnt, int n) {
    int d = threadIdx.x;
    int c0 = blockIdx.x * POOL_CHUNK;
    if (c0 >= n) return;
    int c1 = min(c0 + POOL_CHUNK, n);
    float acc = 0.f, cc = 0.f;
    int g_cur = batch[c0];
    for (int i = c0; i < c1; ++i) {
        int g = batch[i];
        if (g != g_cur) {
            atomicAdd(&sums[g_cur * 128 + d], acc);
            if (d == 0) atomicAdd(&cnt[g_cur], cc);
            acc = 0.f; cc = 0.f; g_cur = g;
        }
        acc += h[(size_t)i * 128 + d];
        cc += 1.f;
    }
    atomicAdd(&sums[g_cur * 128 + d], acc);
    if (d == 0) atomicAdd(&cnt[g_cur], cc);
}

// One block per graph: pooled mean -> Linear+ReLU -> dot+sigmoid.
__global__ __launch_bounds__(128) void k_head(const float* __restrict__ sums,
                                              const float* __restrict__ cnt,
                                              const float* __restrict__ Wh1,
                                              const float* __restrict__ bh1,
                                              const float* __restrict__ Wh2,
                                              const float* __restrict__ bh2,
                                              float* __restrict__ out) {
    int g = blockIdx.x;
    int d = threadIdx.x;
    __shared__ float sp[128];
    __shared__ float red[128];
    float c = fmaxf(cnt[g], 1.0f);
    sp[d] = sums[g * 128 + d] / c;
    __syncthreads();
    float acc = bh1[d];
    for (int k = 0; k < 128; ++k) acc += sp[k] * Wh1[k * 128 + d];
    float z = fmaxf(acc, 0.f);
    red[d] = z * Wh2[d];
    __syncthreads();
    for (int off = 64; off > 0; off >>= 1) {
        if (d < off) red[d] += red[d + off];
        __syncthreads();
    }
    if (d == 0) out[g] = 1.f / (1.f + expf(-(red[0] + bh2[0])));
}

extern "C" void kernel_launch(void* const* d_in, const int* in_sizes, int n_in,
                              void* d_out, int out_size, void* d_ws,
                              size_t ws_size, hipStream_t stream) {
    const float* x    = (const float*)d_in[0];
    const int*   ei   = (const int*)d_in[1];
    const int*   batch= (const int*)d_in[2];
    const float* W1   = (const float*)d_in[3];
    const float* b1   = (const float*)d_in[4];
    const float* W2   = (const float*)d_in[5];
    const float* b2   = (const float*)d_in[6];
    const float* Wh1  = (const float*)d_in[7];
    const float* bh1  = (const float*)d_in[8];
    const float* Wh2  = (const float*)d_in[9];
    const float* bh2  = (const float*)d_in[10];
    float* out = (float*)d_out;

    const int n  = in_sizes[0] / 128;  // 50000
    const int ne = in_sizes[1] / 2;    // 800000
    const int* src = ei;
    const int* dst = ei + ne;

    char* p = (char*)d_ws;
    int* count     = (int*)p;  p += (size_t)n * 4;
    int* row_start = (int*)p;  p += (size_t)(n + 1) * 4;
    int* csr       = (int*)p;  p += (size_t)ne * 4;
    float* dinv    = (float*)p; p += (size_t)n * 4;
    int* blk_sums  = (int*)p;  p += 256 * 4;
    p = (char*)(((uintptr_t)p + 15) & ~(uintptr_t)15);
    unsigned short* hbf = (unsigned short*)p; p += (size_t)n * 128 * 2;
    p = (char*)(((uintptr_t)p + 15) & ~(uintptr_t)15);
    float* buf1 = (float*)p;   p += (size_t)n * 128 * 4;
    float* sums = (float*)p;   p += (size_t)64 * 128 * 4;
    float* cnt  = (float*)p;

    int nb_n = (n + 255) / 256;  // 196 scan blocks (<=256)
    int nb_e = (ne + 255) / 256;
    int nb_g = (n + 63) / 64;
    int nb_a = (n + 3) / 4;
    int nb_p = (n + POOL_CHUNK - 1) / POOL_CHUNK;

    // CSR build + norms (hierarchical scan)
    k_zero<<<nb_n, 256, 0, stream>>>(count, sums, cnt, n);
    k_count<<<nb_e, 256, 0, stream>>>(dst, count, ne);
    k_scan1<<<nb_n, 256, 0, stream>>>(count, row_start, blk_sums, n);
    k_scan2<<<1, 256, 0, stream>>>(blk_sums, nb_n);
    k_scan3<<<nb_n, 256, 0, stream>>>(count, row_start, blk_sums, dinv, n, ne);
    k_fill<<<nb_e, 256, 0, stream>>>(src, dst, row_start, count, csr, ne);

    // conv1
    k_gemm128<<<nb_g, 256, 0, stream>>>(x, W1, hbf, n);
    k_agg<<<nb_a, 256, 0, stream>>>(hbf, dinv, csr, row_start, b1, buf1, n);

    // conv2
    k_gemm128<<<nb_g, 256, 0, stream>>>(buf1, W2, hbf, n);
    k_agg<<<nb_a, 256, 0, stream>>>(hbf, dinv, csr, row_start, b2, buf1, n);

    // pool + head
    k_pool<<<nb_p, 128, 0, stream>>>(buf1, batch, sums, cnt, n);
    k_head<<<64, 128, 0, stream>>>(sums, cnt, Wh1, bh1, Wh2, bh2, out);
}

// Round 8
// 288.617 us; speedup vs baseline: 10.4186x; 1.2237x over previous
//
#include <hip/hip_runtime.h>

// ---------------------------------------------------------------------------
// GCN forward, round 4 (resubmit after infra failure): MFMA GEMMs.
// R3 counters: k_gemm128 2x65us, LDS=96KB -> 1 block/CU, occupancy 8.4%,
// VALUBusy 24% (latency-bound). -> bf16 MFMA 16x16x32 GEMM, no LDS, A-frags
// from bf16 activations, B-frags from pre-transposed bf16 W^T. All GEMM/agg
// accumulation stays f32; activations stored bf16 end-to-end.
// ---------------------------------------------------------------------------

typedef __attribute__((ext_vector_type(8))) short bf16x8;
typedef __attribute__((ext_vector_type(4))) float f32x4;

__device__ inline unsigned short f2bf(float f) {
    union { float f; unsigned int u; } c; c.f = f;
    unsigned int u = c.u + (0x7fffu + ((c.u >> 16) & 1u));  // RNE
    return (unsigned short)(u >> 16);
}
__device__ inline float bf2f(unsigned short b) {
    union { unsigned int u; float f; } c; c.u = ((unsigned int)b) << 16;
    return c.f;
}

__global__ __launch_bounds__(256) void k_zero(int* __restrict__ count,
                                              float* __restrict__ sums,
                                              float* __restrict__ cnt, int n) {
    int i = blockIdx.x * 256 + threadIdx.x;
    if (i < n) count[i] = 0;
    if (i < 64 * 128) sums[i] = 0.0f;
    if (i < 64) cnt[i] = 0.0f;
}

__global__ __launch_bounds__(256) void k_count(const int* __restrict__ dst,
                                               int* __restrict__ count, int ne) {
    int e = blockIdx.x * 256 + threadIdx.x;
    if (e < ne) atomicAdd(&count[dst[e]], 1);
}

__global__ __launch_bounds__(256) void k_scan1(const int* __restrict__ count,
                                               int* __restrict__ row_start,
                                               int* __restrict__ blk_sums,
                                               int n) {
    __shared__ int ps[256];
    int tid = threadIdx.x;
    int i = blockIdx.x * 256 + tid;
    int c = (i < n) ? count[i] : 0;
    ps[tid] = c;
    __syncthreads();
    for (int off = 1; off < 256; off <<= 1) {
        int v = (tid >= off) ? ps[tid - off] : 0;
        __syncthreads();
        ps[tid] += v;
        __syncthreads();
    }
    if (i < n) row_start[i] = ps[tid] - c;
    if (tid == 255) blk_sums[blockIdx.x] = ps[255];
}

__global__ __launch_bounds__(256) void k_scan2(int* __restrict__ blk_sums,
                                               int nblk) {
    __shared__ int ps[256];
    int tid = threadIdx.x;
    int c = (tid < nblk) ? blk_sums[tid] : 0;
    ps[tid] = c;
    __syncthreads();
    for (int off = 1; off < 256; off <<= 1) {
        int v = (tid >= off) ? ps[tid - off] : 0;
        __syncthreads();
        ps[tid] += v;
        __syncthreads();
    }
    if (tid < nblk) blk_sums[tid] = ps[tid] - c;
}

__global__ __launch_bounds__(256) void k_scan3(int* __restrict__ count,
                                               int* __restrict__ row_start,
                                               const int* __restrict__ blk_sums,
                                               float* __restrict__ dinv,
                                               int n, int ne) {
    int i = blockIdx.x * 256 + threadIdx.x;
    if (i == 0) row_start[n] = ne;
    if (i >= n) return;
    row_start[i] += blk_sums[blockIdx.x];
    int c = count[i];
    dinv[i] = rsqrtf((float)c + 1.0f);
    count[i] = 0;
}

__global__ __launch_bounds__(256) void k_fill(const int* __restrict__ src,
                                              const int* __restrict__ dst,
                                              const int* __restrict__ row_start,
                                              int* __restrict__ cursor,
                                              int* __restrict__ csr, int ne) {
    int e = blockIdx.x * 256 + threadIdx.x;
    if (e >= ne) return;
    int d = dst[e];
    int pos = atomicAdd(&cursor[d], 1);
    csr[row_start[d] + pos] = src[e];
}

// x (f32) -> bf16, 4 elems/thread
__global__ __launch_bounds__(256) void k_castx(const float* __restrict__ X,
                                               unsigned short* __restrict__ Xb,
                                               int n4) {
    int i = blockIdx.x * 256 + threadIdx.x;
    if (i >= n4) return;
    float4 v = ((const float4*)X)[i];
    ushort4 o;
    o.x = f2bf(v.x); o.y = f2bf(v.y); o.z = f2bf(v.z); o.w = f2bf(v.w);
    ((ushort4*)Xb)[i] = o;
}

// Wt[n][k] = bf16(W[k][n]); 128x128, tiny (W L2-resident after first lines).
__global__ __launch_bounds__(256) void k_castw(const float* __restrict__ W,
                                               unsigned short* __restrict__ Wt) {
    int tid = blockIdx.x * 256 + threadIdx.x;  // 16384
    int nn = tid >> 7, kk = tid & 127;
    Wt[tid] = f2bf(W[kk * 128 + nn]);
}

// Y[M x 128](bf16) = X[M x 128](bf16) @ W (given as Wt = W^T bf16 [128][128]).
// Block = 256 thr = 4 waves, 64 rows. Wave w: cols [w*32, w*32+32).
// MFMA 16x16x32 bf16, f32 accum. A: row=l&15, k=(l>>4)*8+j. D: col=l&15,
// row=(l>>4)*4+reg (m89-verified layouts).
__global__ __launch_bounds__(256) void k_gemm_mfma(const short* __restrict__ Xb,
                                                   const short* __restrict__ Wt,
                                                   unsigned short* __restrict__ Yb,
                                                   int n_rows) {
    int wid = threadIdx.x >> 6;
    int lane = threadIdx.x & 63;
    int r = lane & 15, q = lane >> 4;
    int m0 = blockIdx.x * 64;
    int n0 = wid * 32;

    // B fragments: [ntile][kstep], reused across all 4 row-tiles
    bf16x8 bfr[2][4];
#pragma unroll
    for (int nt = 0; nt < 2; ++nt)
#pragma unroll
        for (int ks = 0; ks < 4; ++ks)
            bfr[nt][ks] = *(const bf16x8*)(Wt + (size_t)(n0 + nt * 16 + r) * 128 +
                                           ks * 32 + q * 8);

#pragma unroll
    for (int rt = 0; rt < 4; ++rt) {
        int row = m0 + rt * 16 + r;
        int rl = min(row, n_rows - 1);  // clamp: loads stay in-bounds
        const short* xrow = Xb + (size_t)rl * 128;
        f32x4 acc0 = {0.f, 0.f, 0.f, 0.f};
        f32x4 acc1 = {0.f, 0.f, 0.f, 0.f};
#pragma unroll
        for (int ks = 0; ks < 4; ++ks) {
            bf16x8 a = *(const bf16x8*)(xrow + ks * 32 + q * 8);
            acc0 = __builtin_amdgcn_mfma_f32_16x16x32_bf16(a, bfr[0][ks], acc0, 0, 0, 0);
            acc1 = __builtin_amdgcn_mfma_f32_16x16x32_bf16(a, bfr[1][ks], acc1, 0, 0, 0);
        }
#pragma unroll
        for (int v = 0; v < 4; ++v) {
            int orow = m0 + rt * 16 + q * 4 + v;
            if (orow < n_rows) {
                Yb[(size_t)orow * 128 + n0 + r]      = f2bf(acc0[v]);
                Yb[(size_t)orow * 128 + n0 + 16 + r] = f2bf(acc1[v]);
            }
        }
    }
}

// out[d][:] = bf16( relu( sum_e h[src]*dinv[s]*dinv[d] + h[d]*dinv[d]^2 + b ) )
// h bf16; one wave/node; lane = 2 bf16 (one dword); srcs shfl-broadcast.
__global__ __launch_bounds__(256) void k_agg(const unsigned short* __restrict__ h,
                                             const float* __restrict__ dinv,
                                             const int* __restrict__ csr,
                                             const int* __restrict__ row_start,
                                             const float* __restrict__ bias,
                                             unsigned short* __restrict__ out,
                                             int n) {
    int node = blockIdx.x * 4 + (threadIdx.x >> 6);
    if (node >= n) return;
    int lane = threadIdx.x & 63;
    const unsigned int* h2 = (const unsigned int*)h;

    union { unsigned int u; float f; } cv;
    float di = dinv[node];

    unsigned int hu = h2[(size_t)node * 64 + lane];
    cv.u = hu << 16;         float hx = cv.f;
    cv.u = hu & 0xffff0000u; float hy = cv.f;
    float ax = hx * di * di;
    float ay = hy * di * di;

    int beg = row_start[node];
    int end = row_start[node + 1];
    int deg = end - beg;

    int mysrc = (lane < deg) ? csr[beg + lane] : 0;
    float myw = (lane < deg) ? dinv[mysrc] : 0.0f;

    int m = min(deg, 64);
    for (int e = 0; e < m; ++e) {
        int s = __shfl(mysrc, e);
        float w = __shfl(myw, e) * di;
        unsigned int u = h2[(size_t)s * 64 + lane];
        cv.u = u << 16;          float vx = cv.f;
        cv.u = u & 0xffff0000u;  float vy = cv.f;
        ax += vx * w;
        ay += vy * w;
    }
    for (int j = beg + 64; j < end; ++j) {
        int s = csr[j];
        float w = dinv[s] * di;
        unsigned int u = h2[(size_t)s * 64 + lane];
        cv.u = u << 16;          float vx = cv.f;
        cv.u = u & 0xffff0000u;  float vy = cv.f;
        ax += vx * w;
        ay += vy * w;
    }

    float2 bv = ((const float2*)bias)[lane];
    float ox = fmaxf(ax + bv.x, 0.0f);
    float oy = fmaxf(ay + bv.y, 0.0f);
    unsigned int pack = (unsigned int)f2bf(ox) | ((unsigned int)f2bf(oy) << 16);
    ((unsigned int*)out)[(size_t)node * 64 + lane] = pack;
}

// Segmented mean-pool over sorted batch; h is bf16.
#define POOL_CHUNK 64
__global__ __launch_bounds__(128) void k_pool(const unsigned short* __restrict__ h,
                                              const int* __restrict__ batch,
                                              float* __restrict__ sums,
                                              float* __restrict__ cnt, int n) {
    int d = threadIdx.x;
    int c0 = blockIdx.x * POOL_CHUNK;
    if (c0 >= n) return;
    int c1 = min(c0 + POOL_CHUNK, n);
    float acc = 0.f, cc = 0.f;
    int g_cur = batch[c0];
    for (int i = c0; i < c1; ++i) {
        int g = batch[i];
        if (g != g_cur) {
            atomicAdd(&sums[g_cur * 128 + d], acc);
            if (d == 0) atomicAdd(&cnt[g_cur], cc);
            acc = 0.f; cc = 0.f; g_cur = g;
        }
        acc += bf2f(h[(size_t)i * 128 + d]);
        cc += 1.f;
    }
    atomicAdd(&sums[g_cur * 128 + d], acc);
    if (d == 0) atomicAdd(&cnt[g_cur], cc);
}

// One block per graph: pooled mean -> Linear+ReLU -> dot+sigmoid.
__global__ __launch_bounds__(128) void k_head(const float* __restrict__ sums,
                                              const float* __restrict__ cnt,
                                              const float* __restrict__ Wh1,
                                              const float* __restrict__ bh1,
                                              const float* __restrict__ Wh2,
                                              const float* __restrict__ bh2,
                                              float* __restrict__ out) {
    int g = blockIdx.x;
    int d = threadIdx.x;
    __shared__ float sp[128];
    __shared__ float red[128];
    float c = fmaxf(cnt[g], 1.0f);
    sp[d] = sums[g * 128 + d] / c;
    __syncthreads();
    float acc = bh1[d];
    for (int k = 0; k < 128; ++k) acc += sp[k] * Wh1[k * 128 + d];
    float z = fmaxf(acc, 0.f);
    red[d] = z * Wh2[d];
    __syncthreads();
    for (int off = 64; off > 0; off >>= 1) {
        if (d < off) red[d] += red[d + off];
        __syncthreads();
    }
    if (d == 0) out[g] = 1.f / (1.f + expf(-(red[0] + bh2[0])));
}

extern "C" void kernel_launch(void* const* d_in, const int* in_sizes, int n_in,
                              void* d_out, int out_size, void* d_ws,
                              size_t ws_size, hipStream_t stream) {
    const float* x    = (const float*)d_in[0];
    const int*   ei   = (const int*)d_in[1];
    const int*   batch= (const int*)d_in[2];
    const float* W1   = (const float*)d_in[3];
    const float* b1   = (const float*)d_in[4];
    const float* W2   = (const float*)d_in[5];
    const float* b2   = (const float*)d_in[6];
    const float* Wh1  = (const float*)d_in[7];
    const float* bh1  = (const float*)d_in[8];
    const float* Wh2  = (const float*)d_in[9];
    const float* bh2  = (const float*)d_in[10];
    float* out = (float*)d_out;

    const int n  = in_sizes[0] / 128;  // 50000
    const int ne = in_sizes[1] / 2;    // 800000
    const int* src = ei;
    const int* dst = ei + ne;

    char* p = (char*)d_ws;
    int* count     = (int*)p;  p += (size_t)n * 4;
    int* row_start = (int*)p;  p += (size_t)(n + 1) * 4;
    int* csr       = (int*)p;  p += (size_t)ne * 4;
    float* dinv    = (float*)p; p += (size_t)n * 4;
    int* blk_sums  = (int*)p;  p += 256 * 4;
    p = (char*)(((uintptr_t)p + 15) & ~(uintptr_t)15);
    unsigned short* xb  = (unsigned short*)p; p += (size_t)n * 128 * 2;
    unsigned short* Wt1 = (unsigned short*)p; p += 128 * 128 * 2;
    unsigned short* Wt2 = (unsigned short*)p; p += 128 * 128 * 2;
    unsigned short* hbf = (unsigned short*)p; p += (size_t)n * 128 * 2;
    unsigned short* abf = (unsigned short*)p; p += (size_t)n * 128 * 2;
    p = (char*)(((uintptr_t)p + 15) & ~(uintptr_t)15);
    float* sums = (float*)p;   p += (size_t)64 * 128 * 4;
    float* cnt  = (float*)p;

    int nb_n = (n + 255) / 256;
    int nb_e = (ne + 255) / 256;
    int nb_g = (n + 63) / 64;      // MFMA GEMM blocks (64 rows each)
    int nb_a = (n + 3) / 4;
    int nb_c = (n * 32 + 255) / 256;  // castx: n*128/4 threads
    int nb_p = (n + POOL_CHUNK - 1) / POOL_CHUNK;

    // CSR build + norms (hierarchical scan)
    k_zero<<<nb_n, 256, 0, stream>>>(count, sums, cnt, n);
    k_count<<<nb_e, 256, 0, stream>>>(dst, count, ne);
    k_scan1<<<nb_n, 256, 0, stream>>>(count, row_start, blk_sums, n);
    k_scan2<<<1, 256, 0, stream>>>(blk_sums, nb_n);
    k_scan3<<<nb_n, 256, 0, stream>>>(count, row_start, blk_sums, dinv, n, ne);
    k_fill<<<nb_e, 256, 0, stream>>>(src, dst, row_start, count, csr, ne);

    // casts
    k_castx<<<nb_c, 256, 0, stream>>>(x, xb, n * 32);
    k_castw<<<64, 256, 0, stream>>>(W1, Wt1);
    k_castw<<<64, 256, 0, stream>>>(W2, Wt2);

    // conv1
    k_gemm_mfma<<<nb_g, 256, 0, stream>>>((const short*)xb, (const short*)Wt1, hbf, n);
    k_agg<<<nb_a, 256, 0, stream>>>(hbf, dinv, csr, row_start, b1, abf, n);

    // conv2
    k_gemm_mfma<<<nb_g, 256, 0, stream>>>((const short*)abf, (const short*)Wt2, hbf, n);
    k_agg<<<nb_a, 256, 0, stream>>>(hbf, dinv, csr, row_start, b2, abf, n);

    // pool + head
    k_pool<<<nb_p, 128, 0, stream>>>(abf, batch, sums, cnt, n);
    k_head<<<64, 128, 0, stream>>>(sums, cnt, Wh1, bh1, Wh2, bh2, out);
}

// Round 9
// 244.992 us; speedup vs baseline: 12.2738x; 1.1781x over previous
//
#include <hip/hip_runtime.h>

// ---------------------------------------------------------------------------
// GCN forward, round 5: k_agg memory-level parallelism + fused x-cast.
// R4 counters: k_agg 2x60.6us, FETCH=115MB @1.9TB/s, VALUBusy 25%, occ 62%
// -> latency-bound gather (1 row-load in flight per wave). Unroll edge loop
// x4 (4 independent 256B loads in flight). GEMM1 reads f32 x directly
// (in-register bf16 convert) - k_castx eliminated.
// ---------------------------------------------------------------------------

typedef __attribute__((ext_vector_type(8))) short bf16x8;
typedef __attribute__((ext_vector_type(4))) float f32x4;

__device__ inline unsigned short f2bf(float f) {
    union { float f; unsigned int u; } c; c.f = f;
    unsigned int u = c.u + (0x7fffu + ((c.u >> 16) & 1u));  // RNE
    return (unsigned short)(u >> 16);
}
__device__ inline float bf2f(unsigned short b) {
    union { unsigned int u; float f; } c; c.u = ((unsigned int)b) << 16;
    return c.f;
}

__global__ __launch_bounds__(256) void k_zero(int* __restrict__ count,
                                              float* __restrict__ sums,
                                              float* __restrict__ cnt, int n) {
    int i = blockIdx.x * 256 + threadIdx.x;
    if (i < n) count[i] = 0;
    if (i < 64 * 128) sums[i] = 0.0f;
    if (i < 64) cnt[i] = 0.0f;
}

__global__ __launch_bounds__(256) void k_count(const int* __restrict__ dst,
                                               int* __restrict__ count, int ne) {
    int e = blockIdx.x * 256 + threadIdx.x;
    if (e < ne) atomicAdd(&count[dst[e]], 1);
}

__global__ __launch_bounds__(256) void k_scan1(const int* __restrict__ count,
                                               int* __restrict__ row_start,
                                               int* __restrict__ blk_sums,
                                               int n) {
    __shared__ int ps[256];
    int tid = threadIdx.x;
    int i = blockIdx.x * 256 + tid;
    int c = (i < n) ? count[i] : 0;
    ps[tid] = c;
    __syncthreads();
    for (int off = 1; off < 256; off <<= 1) {
        int v = (tid >= off) ? ps[tid - off] : 0;
        __syncthreads();
        ps[tid] += v;
        __syncthreads();
    }
    if (i < n) row_start[i] = ps[tid] - c;
    if (tid == 255) blk_sums[blockIdx.x] = ps[255];
}

__global__ __launch_bounds__(256) void k_scan2(int* __restrict__ blk_sums,
                                               int nblk) {
    __shared__ int ps[256];
    int tid = threadIdx.x;
    int c = (tid < nblk) ? blk_sums[tid] : 0;
    ps[tid] = c;
    __syncthreads();
    for (int off = 1; off < 256; off <<= 1) {
        int v = (tid >= off) ? ps[tid - off] : 0;
        __syncthreads();
        ps[tid] += v;
        __syncthreads();
    }
    if (tid < nblk) blk_sums[tid] = ps[tid] - c;
}

__global__ __launch_bounds__(256) void k_scan3(int* __restrict__ count,
                                               int* __restrict__ row_start,
                                               const int* __restrict__ blk_sums,
                                               float* __restrict__ dinv,
                                               int n, int ne) {
    int i = blockIdx.x * 256 + threadIdx.x;
    if (i == 0) row_start[n] = ne;
    if (i >= n) return;
    row_start[i] += blk_sums[blockIdx.x];
    int c = count[i];
    dinv[i] = rsqrtf((float)c + 1.0f);
    count[i] = 0;
}

__global__ __launch_bounds__(256) void k_fill(const int* __restrict__ src,
                                              const int* __restrict__ dst,
                                              const int* __restrict__ row_start,
                                              int* __restrict__ cursor,
                                              int* __restrict__ csr, int ne) {
    int e = blockIdx.x * 256 + threadIdx.x;
    if (e >= ne) return;
    int d = dst[e];
    int pos = atomicAdd(&cursor[d], 1);
    csr[row_start[d] + pos] = src[e];
}

// Wt[n][k] = bf16(W[k][n]); 128x128.
__global__ __launch_bounds__(256) void k_castw(const float* __restrict__ W,
                                               unsigned short* __restrict__ Wt) {
    int tid = blockIdx.x * 256 + threadIdx.x;  // 16384
    int nn = tid >> 7, kk = tid & 127;
    Wt[tid] = f2bf(W[kk * 128 + nn]);
}

// Y[M x 128](bf16) = X[M x 128] @ W (Wt = W^T bf16 [128][128]).
// F32IN: X is f32 (converted in-register); else X is bf16.
// Block = 4 waves, 64 rows; wave w owns cols [w*32, w*32+32).
// MFMA 16x16x32 bf16, f32 accum; m89-verified A/D layouts.
template <bool F32IN>
__global__ __launch_bounds__(256) void k_gemm_mfma(const void* __restrict__ Xin,
                                                   const short* __restrict__ Wt,
                                                   unsigned short* __restrict__ Yb,
                                                   int n_rows) {
    int wid = threadIdx.x >> 6;
    int lane = threadIdx.x & 63;
    int r = lane & 15, q = lane >> 4;
    int m0 = blockIdx.x * 64;
    int n0 = wid * 32;

    bf16x8 bfr[2][4];
#pragma unroll
    for (int nt = 0; nt < 2; ++nt)
#pragma unroll
        for (int ks = 0; ks < 4; ++ks)
            bfr[nt][ks] = *(const bf16x8*)(Wt + (size_t)(n0 + nt * 16 + r) * 128 +
                                           ks * 32 + q * 8);

#pragma unroll
    for (int rt = 0; rt < 4; ++rt) {
        int row = m0 + rt * 16 + r;
        int rl = min(row, n_rows - 1);  // clamp: loads stay in-bounds
        f32x4 acc0 = {0.f, 0.f, 0.f, 0.f};
        f32x4 acc1 = {0.f, 0.f, 0.f, 0.f};
#pragma unroll
        for (int ks = 0; ks < 4; ++ks) {
            bf16x8 a;
            if constexpr (F32IN) {
                const float* xr = (const float*)Xin + (size_t)rl * 128 + ks * 32 + q * 8;
                float4 f0 = *(const float4*)xr;
                float4 f1 = *(const float4*)(xr + 4);
                a[0] = (short)f2bf(f0.x); a[1] = (short)f2bf(f0.y);
                a[2] = (short)f2bf(f0.z); a[3] = (short)f2bf(f0.w);
                a[4] = (short)f2bf(f1.x); a[5] = (short)f2bf(f1.y);
                a[6] = (short)f2bf(f1.z); a[7] = (short)f2bf(f1.w);
            } else {
                a = *(const bf16x8*)((const short*)Xin + (size_t)rl * 128 + ks * 32 + q * 8);
            }
            acc0 = __builtin_amdgcn_mfma_f32_16x16x32_bf16(a, bfr[0][ks], acc0, 0, 0, 0);
            acc1 = __builtin_amdgcn_mfma_f32_16x16x32_bf16(a, bfr[1][ks], acc1, 0, 0, 0);
        }
#pragma unroll
        for (int v = 0; v < 4; ++v) {
            int orow = m0 + rt * 16 + q * 4 + v;
            if (orow < n_rows) {
                Yb[(size_t)orow * 128 + n0 + r]      = f2bf(acc0[v]);
                Yb[(size_t)orow * 128 + n0 + 16 + r] = f2bf(acc1[v]);
            }
        }
    }
}

// out[d][:] = bf16( relu( sum_e h[src]*dinv[s]*dinv[d] + h[d]*dinv[d]^2 + b ) )
// h bf16; one wave/node; lane = 2 bf16 (one dword); srcs shfl-broadcast.
// Edge loop unrolled x4 for memory-level parallelism.
__global__ __launch_bounds__(256) void k_agg(const unsigned short* __restrict__ h,
                                             const float* __restrict__ dinv,
                                             const int* __restrict__ csr,
                                             const int* __restrict__ row_start,
                                             const float* __restrict__ bias,
                                             unsigned short* __restrict__ out,
                                             int n) {
    int node = blockIdx.x * 4 + (threadIdx.x >> 6);
    if (node >= n) return;
    int lane = threadIdx.x & 63;
    const unsigned int* h2 = (const unsigned int*)h;

    union { unsigned int u; float f; } cv;
    float di = dinv[node];

    unsigned int hu = h2[(size_t)node * 64 + lane];
    cv.u = hu << 16;         float hx = cv.f;
    cv.u = hu & 0xffff0000u; float hy = cv.f;
    float ax = hx * di * di;
    float ay = hy * di * di;

    int beg = row_start[node];
    int end = row_start[node + 1];
    int deg = end - beg;

    int mysrc = (lane < deg) ? csr[beg + lane] : 0;
    float myw = ((lane < deg) ? dinv[mysrc] : 0.0f) * di;

    int m = min(deg, 64);
    int e = 0;
    for (; e + 4 <= m; e += 4) {
        int s0 = __shfl(mysrc, e);
        int s1 = __shfl(mysrc, e + 1);
        int s2 = __shfl(mysrc, e + 2);
        int s3 = __shfl(mysrc, e + 3);
        float w0 = __shfl(myw, e);
        float w1 = __shfl(myw, e + 1);
        float w2 = __shfl(myw, e + 2);
        float w3 = __shfl(myw, e + 3);
        unsigned int u0 = h2[(size_t)s0 * 64 + lane];
        unsigned int u1 = h2[(size_t)s1 * 64 + lane];
        unsigned int u2 = h2[(size_t)s2 * 64 + lane];
        unsigned int u3 = h2[(size_t)s3 * 64 + lane];
        cv.u = u0 << 16;         ax += cv.f * w0;
        cv.u = u0 & 0xffff0000u; ay += cv.f * w0;
        cv.u = u1 << 16;         ax += cv.f * w1;
        cv.u = u1 & 0xffff0000u; ay += cv.f * w1;
        cv.u = u2 << 16;         ax += cv.f * w2;
        cv.u = u2 & 0xffff0000u; ay += cv.f * w2;
        cv.u = u3 << 16;         ax += cv.f * w3;
        cv.u = u3 & 0xffff0000u; ay += cv.f * w3;
    }
    for (; e < m; ++e) {
        int s = __shfl(mysrc, e);
        float w = __shfl(myw, e);
        unsigned int u = h2[(size_t)s * 64 + lane];
        cv.u = u << 16;          ax += cv.f * w;
        cv.u = u & 0xffff0000u;  ay += cv.f * w;
    }
    for (int j = beg + 64; j < end; ++j) {  // rare: deg > 64
        int s = csr[j];
        float w = dinv[s] * di;
        unsigned int u = h2[(size_t)s * 64 + lane];
        cv.u = u << 16;          ax += cv.f * w;
        cv.u = u & 0xffff0000u;  ay += cv.f * w;
    }

    float2 bv = ((const float2*)bias)[lane];
    float ox = fmaxf(ax + bv.x, 0.0f);
    float oy = fmaxf(ay + bv.y, 0.0f);
    unsigned int pack = (unsigned int)f2bf(ox) | ((unsigned int)f2bf(oy) << 16);
    ((unsigned int*)out)[(size_t)node * 64 + lane] = pack;
}

// Segmented mean-pool over sorted batch; h is bf16.
#define POOL_CHUNK 64
__global__ __launch_bounds__(128) void k_pool(const unsigned short* __restrict__ h,
                                              const int* __restrict__ batch,
                                              float* __restrict__ sums,
                                              float* __restrict__ cnt, int n) {
    int d = threadIdx.x;
    int c0 = blockIdx.x * POOL_CHUNK;
    if (c0 >= n) return;
    int c1 = min(c0 + POOL_CHUNK, n);
    float acc = 0.f, cc = 0.f;
    int g_cur = batch[c0];
    for (int i = c0; i < c1; ++i) {
        int g = batch[i];
        if (g != g_cur) {
            atomicAdd(&sums[g_cur * 128 + d], acc);
            if (d == 0) atomicAdd(&cnt[g_cur], cc);
            acc = 0.f; cc = 0.f; g_cur = g;
        }
        acc += bf2f(h[(size_t)i * 128 + d]);
        cc += 1.f;
    }
    atomicAdd(&sums[g_cur * 128 + d], acc);
    if (d == 0) atomicAdd(&cnt[g_cur], cc);
}

// One block per graph: pooled mean -> Linear+ReLU -> dot+sigmoid.
__global__ __launch_bounds__(128) void k_head(const float* __restrict__ sums,
                                              const float* __restrict__ cnt,
                                              const float* __restrict__ Wh1,
                                              const float* __restrict__ bh1,
                                              const float* __restrict__ Wh2,
                                              const float* __restrict__ bh2,
                                              float* __restrict__ out) {
    int g = blockIdx.x;
    int d = threadIdx.x;
    __shared__ float sp[128];
    __shared__ float red[128];
    float c = fmaxf(cnt[g], 1.0f);
    sp[d] = sums[g * 128 + d] / c;
    __syncthreads();
    float acc = bh1[d];
    for (int k = 0; k < 128; ++k) acc += sp[k] * Wh1[k * 128 + d];
    float z = fmaxf(acc, 0.f);
    red[d] = z * Wh2[d];
    __syncthreads();
    for (int off = 64; off > 0; off >>= 1) {
        if (d < off) red[d] += red[d + off];
        __syncthreads();
    }
    if (d == 0) out[g] = 1.f / (1.f + expf(-(red[0] + bh2[0])));
}

extern "C" void kernel_launch(void* const* d_in, const int* in_sizes, int n_in,
                              void* d_out, int out_size, void* d_ws,
                              size_t ws_size, hipStream_t stream) {
    const float* x    = (const float*)d_in[0];
    const int*   ei   = (const int*)d_in[1];
    const int*   batch= (const int*)d_in[2];
    const float* W1   = (const float*)d_in[3];
    const float* b1   = (const float*)d_in[4];
    const float* W2   = (const float*)d_in[5];
    const float* b2   = (const float*)d_in[6];
    const float* Wh1  = (const float*)d_in[7];
    const float* bh1  = (const float*)d_in[8];
    const float* Wh2  = (const float*)d_in[9];
    const float* bh2  = (const float*)d_in[10];
    float* out = (float*)d_out;

    const int n  = in_sizes[0] / 128;  // 50000
    const int ne = in_sizes[1] / 2;    // 800000
    const int* src = ei;
    const int* dst = ei + ne;

    char* p = (char*)d_ws;
    int* count     = (int*)p;  p += (size_t)n * 4;
    int* row_start = (int*)p;  p += (size_t)(n + 1) * 4;
    int* csr       = (int*)p;  p += (size_t)ne * 4;
    float* dinv    = (float*)p; p += (size_t)n * 4;
    int* blk_sums  = (int*)p;  p += 256 * 4;
    p = (char*)(((uintptr_t)p + 15) & ~(uintptr_t)15);
    unsigned short* Wt1 = (unsigned short*)p; p += 128 * 128 * 2;
    unsigned short* Wt2 = (unsigned short*)p; p += 128 * 128 * 2;
    unsigned short* hbf = (unsigned short*)p; p += (size_t)n * 128 * 2;
    unsigned short* abf = (unsigned short*)p; p += (size_t)n * 128 * 2;
    p = (char*)(((uintptr_t)p + 15) & ~(uintptr_t)15);
    float* sums = (float*)p;   p += (size_t)64 * 128 * 4;
    float* cnt  = (float*)p;

    int nb_n = (n + 255) / 256;
    int nb_e = (ne + 255) / 256;
    int nb_g = (n + 63) / 64;
    int nb_a = (n + 3) / 4;
    int nb_p = (n + POOL_CHUNK - 1) / POOL_CHUNK;

    // CSR build + norms (hierarchical scan)
    k_zero<<<nb_n, 256, 0, stream>>>(count, sums, cnt, n);
    k_count<<<nb_e, 256, 0, stream>>>(dst, count, ne);
    k_scan1<<<nb_n, 256, 0, stream>>>(count, row_start, blk_sums, n);
    k_scan2<<<1, 256, 0, stream>>>(blk_sums, nb_n);
    k_scan3<<<nb_n, 256, 0, stream>>>(count, row_start, blk_sums, dinv, n, ne);
    k_fill<<<nb_e, 256, 0, stream>>>(src, dst, row_start, count, csr, ne);

    // weight transpose-casts
    k_castw<<<64, 256, 0, stream>>>(W1, Wt1);
    k_castw<<<64, 256, 0, stream>>>(W2, Wt2);

    // conv1 (GEMM reads f32 x directly)
    k_gemm_mfma<true><<<nb_g, 256, 0, stream>>>((const void*)x, (const short*)Wt1, hbf, n);
    k_agg<<<nb_a, 256, 0, stream>>>(hbf, dinv, csr, row_start, b1, abf, n);

    // conv2
    k_gemm_mfma<false><<<nb_g, 256, 0, stream>>>((const void*)abf, (const short*)Wt2, hbf, n);
    k_agg<<<nb_a, 256, 0, stream>>>(hbf, dinv, csr, row_start, b2, abf, n);

    // pool + head
    k_pool<<<nb_p, 128, 0, stream>>>(abf, batch, sums, cnt, n);
    k_head<<<64, 128, 0, stream>>>(sums, cnt, Wh1, bh1, Wh2, bh2, out);
}

// Round 10
// 204.161 us; speedup vs baseline: 14.7285x; 1.2000x over previous
//
#include <hip/hip_runtime.h>

// ---------------------------------------------------------------------------
// GCN forward, round 6: atomic-free CSR build via 2-level bucket sort.
// R5 counters: k_fill 42.8us, WRITE_SIZE=56MB for 3.2MB payload (random 4B
// scatter + 800k cursor atomics -> write-allocate/coherence amplification);
// k_count same atomic pattern. -> per-block histograms + block-private bucket
// slices (line-filling writes) + per-bucket LDS counting sort.
// ---------------------------------------------------------------------------

#define NB 256    // scatter blocks
#define NBK 256   // buckets (dst>>8; requires n <= 65536)

typedef __attribute__((ext_vector_type(8))) short bf16x8;
typedef __attribute__((ext_vector_type(4))) float f32x4;

__device__ inline unsigned short f2bf(float f) {
    union { float f; unsigned int u; } c; c.f = f;
    unsigned int u = c.u + (0x7fffu + ((c.u >> 16) & 1u));  // RNE
    return (unsigned short)(u >> 16);
}
__device__ inline float bf2f(unsigned short b) {
    union { unsigned int u; float f; } c; c.u = ((unsigned int)b) << 16;
    return c.f;
}

// kA: per-block bucket histogram (LDS) -> hist[block][bucket]; zero sums/cnt.
__global__ __launch_bounds__(256) void k_hist(const int* __restrict__ dst,
                                              int* __restrict__ hist,
                                              float* __restrict__ sums,
                                              float* __restrict__ cnt,
                                              int ne, int chunk) {
    __shared__ int h[NBK];
    int t = threadIdx.x, b = blockIdx.x;
    h[t] = 0;
    int gid = b * 256 + t;
    if (gid < 64 * 128) sums[gid] = 0.0f;
    if (gid < 64) cnt[gid] = 0.0f;
    __syncthreads();
    int e0 = b * chunk, e1 = min(e0 + chunk, ne);
    for (int e = e0 + t; e < e1; e += 256) atomicAdd(&h[dst[e] >> 8], 1);
    __syncthreads();
    hist[b * NBK + t] = h[t];
}

// kB: single block; thread j owns bucket j. Column-scan over blocks ->
// per-(block,bucket) base (in place), bucket starts, row_start[n] sentinel.
__global__ __launch_bounds__(256) void k_scanb(int* __restrict__ hist,
                                               int* __restrict__ bstart,
                                               int* __restrict__ row_start,
                                               int n, int ne) {
    __shared__ int ps[256];
    int j = threadIdx.x;
    int run = 0;
    for (int i = 0; i < NB; ++i) {      // coalesced across j
        int t = hist[i * NBK + j];
        hist[i * NBK + j] = run;
        run += t;
    }
    ps[j] = run;
    __syncthreads();
    for (int off = 1; off < 256; off <<= 1) {
        int v = (j >= off) ? ps[j - off] : 0;
        __syncthreads();
        ps[j] += v;
        __syncthreads();
    }
    int excl = ps[j] - run;   // exclusive bucket start
    bstart[j] = excl;
    if (j == 255) bstart[256] = ps[255];  // = ne
    if (j == 0) row_start[n] = ne;
    for (int i = 0; i < NB; ++i) hist[i * NBK + j] += excl;
}

// kC: scatter edges into bucket regions; each block writes its private
// contiguous slice of every bucket (line-filling). Pack (dst&255)<<24 | src.
__global__ __launch_bounds__(256) void k_scat(const int* __restrict__ src,
                                              const int* __restrict__ dst,
                                              const int* __restrict__ hist,
                                              unsigned int* __restrict__ ebuf,
                                              int ne, int chunk) {
    __shared__ int cur[NBK];
    int t = threadIdx.x, b = blockIdx.x;
    cur[t] = hist[b * NBK + t];
    __syncthreads();
    int e0 = b * chunk, e1 = min(e0 + chunk, ne);
    for (int e = e0 + t; e < e1; e += 256) {
        int d = dst[e];
        int p = atomicAdd(&cur[d >> 8], 1);
        ebuf[p] = ((unsigned int)(d & 255) << 24) | (unsigned int)src[e];
    }
}

// kD: one block per bucket: LDS counting sort by low byte -> csr (bucket-local
// writes), row_start, dinv.
__global__ __launch_bounds__(256) void k_bsort(const unsigned int* __restrict__ ebuf,
                                               const int* __restrict__ bstart,
                                               int* __restrict__ csr,
                                               int* __restrict__ row_start,
                                               float* __restrict__ dinv,
                                               int n) {
    __shared__ int h[NBK];
    __shared__ int sc[NBK];
    int j = threadIdx.x, b = blockIdx.x;
    int s0 = bstart[b], s1 = bstart[b + 1];
    h[j] = 0;
    __syncthreads();
    for (int e = s0 + j; e < s1; e += 256) atomicAdd(&h[ebuf[e] >> 24], 1);
    __syncthreads();
    sc[j] = h[j];
    __syncthreads();
    for (int off = 1; off < 256; off <<= 1) {
        int v = (j >= off) ? sc[j - off] : 0;
        __syncthreads();
        sc[j] += v;
        __syncthreads();
    }
    int excl = sc[j] - h[j];
    int id = b * 256 + j;
    int deg = h[j];
    if (id < n) {
        row_start[id] = s0 + excl;
        dinv[id] = rsqrtf((float)deg + 1.0f);
    }
    __syncthreads();
    h[j] = excl;  // becomes cursor
    __syncthreads();
    for (int e = s0 + j; e < s1; e += 256) {
        unsigned int pk = ebuf[e];
        int p = atomicAdd(&h[pk >> 24], 1);
        csr[s0 + p] = (int)(pk & 0xFFFFFFu >> 0 & 0x00FFFFFFu);
    }
}

// Wt[n][k] = bf16(W[k][n]) for both weight matrices in one launch.
__global__ __launch_bounds__(256) void k_castw(const float* __restrict__ W1,
                                               const float* __restrict__ W2,
                                               unsigned short* __restrict__ Wt1,
                                               unsigned short* __restrict__ Wt2) {
    int tid = blockIdx.x * 256 + threadIdx.x;  // 0..32767
    int i = tid & 16383;
    int nn = i >> 7, kk = i & 127;
    if (tid < 16384) Wt1[i] = f2bf(W1[kk * 128 + nn]);
    else             Wt2[i] = f2bf(W2[kk * 128 + nn]);
}

// Y[M x 128](bf16) = X[M x 128] @ W (Wt = W^T bf16 [128][128]).
// F32IN: X f32 (in-register convert); else bf16. 4 waves, 64 rows/block.
template <bool F32IN>
__global__ __launch_bounds__(256) void k_gemm_mfma(const void* __restrict__ Xin,
                                                   const short* __restrict__ Wt,
                                                   unsigned short* __restrict__ Yb,
                                                   int n_rows) {
    int wid = threadIdx.x >> 6;
    int lane = threadIdx.x & 63;
    int r = lane & 15, q = lane >> 4;
    int m0 = blockIdx.x * 64;
    int n0 = wid * 32;

    bf16x8 bfr[2][4];
#pragma unroll
    for (int nt = 0; nt < 2; ++nt)
#pragma unroll
        for (int ks = 0; ks < 4; ++ks)
            bfr[nt][ks] = *(const bf16x8*)(Wt + (size_t)(n0 + nt * 16 + r) * 128 +
                                           ks * 32 + q * 8);

#pragma unroll
    for (int rt = 0; rt < 4; ++rt) {
        int row = m0 + rt * 16 + r;
        int rl = min(row, n_rows - 1);
        f32x4 acc0 = {0.f, 0.f, 0.f, 0.f};
        f32x4 acc1 = {0.f, 0.f, 0.f, 0.f};
#pragma unroll
        for (int ks = 0; ks < 4; ++ks) {
            bf16x8 a;
            if constexpr (F32IN) {
                const float* xr = (const float*)Xin + (size_t)rl * 128 + ks * 32 + q * 8;
                float4 f0 = *(const float4*)xr;
                float4 f1 = *(const float4*)(xr + 4);
                a[0] = (short)f2bf(f0.x); a[1] = (short)f2bf(f0.y);
                a[2] = (short)f2bf(f0.z); a[3] = (short)f2bf(f0.w);
                a[4] = (short)f2bf(f1.x); a[5] = (short)f2bf(f1.y);
                a[6] = (short)f2bf(f1.z); a[7] = (short)f2bf(f1.w);
            } else {
                a = *(const bf16x8*)((const short*)Xin + (size_t)rl * 128 + ks * 32 + q * 8);
            }
            acc0 = __builtin_amdgcn_mfma_f32_16x16x32_bf16(a, bfr[0][ks], acc0, 0, 0, 0);
            acc1 = __builtin_amdgcn_mfma_f32_16x16x32_bf16(a, bfr[1][ks], acc1, 0, 0, 0);
        }
#pragma unroll
        for (int v = 0; v < 4; ++v) {
            int orow = m0 + rt * 16 + q * 4 + v;
            if (orow < n_rows) {
                Yb[(size_t)orow * 128 + n0 + r]      = f2bf(acc0[v]);
                Yb[(size_t)orow * 128 + n0 + 16 + r] = f2bf(acc1[v]);
            }
        }
    }
}

// out[d][:] = bf16( relu( sum_e h[src]*dinv[s]*dinv[d] + h[d]*dinv[d]^2 + b ) )
// h bf16; one wave/node; lane = 2 bf16 (one dword); srcs shfl-broadcast; x4 MLP.
__global__ __launch_bounds__(256) void k_agg(const unsigned short* __restrict__ h,
                                             const float* __restrict__ dinv,
                                             const int* __restrict__ csr,
                                             const int* __restrict__ row_start,
                                             const float* __restrict__ bias,
                                             unsigned short* __restrict__ out,
                                             int n) {
    int node = blockIdx.x * 4 + (threadIdx.x >> 6);
    if (node >= n) return;
    int lane = threadIdx.x & 63;
    const unsigned int* h2 = (const unsigned int*)h;

    union { unsigned int u; float f; } cv;
    float di = dinv[node];

    unsigned int hu = h2[(size_t)node * 64 + lane];
    cv.u = hu << 16;         float hx = cv.f;
    cv.u = hu & 0xffff0000u; float hy = cv.f;
    float ax = hx * di * di;
    float ay = hy * di * di;

    int beg = row_start[node];
    int end = row_start[node + 1];
    int deg = end - beg;

    int mysrc = (lane < deg) ? csr[beg + lane] : 0;
    float myw = ((lane < deg) ? dinv[mysrc] : 0.0f) * di;

    int m = min(deg, 64);
    int e = 0;
    for (; e + 4 <= m; e += 4) {
        int s0 = __shfl(mysrc, e);
        int s1 = __shfl(mysrc, e + 1);
        int s2 = __shfl(mysrc, e + 2);
        int s3 = __shfl(mysrc, e + 3);
        float w0 = __shfl(myw, e);
        float w1 = __shfl(myw, e + 1);
        float w2 = __shfl(myw, e + 2);
        float w3 = __shfl(myw, e + 3);
        unsigned int u0 = h2[(size_t)s0 * 64 + lane];
        unsigned int u1 = h2[(size_t)s1 * 64 + lane];
        unsigned int u2 = h2[(size_t)s2 * 64 + lane];
        unsigned int u3 = h2[(size_t)s3 * 64 + lane];
        cv.u = u0 << 16;         ax += cv.f * w0;
        cv.u = u0 & 0xffff0000u; ay += cv.f * w0;
        cv.u = u1 << 16;         ax += cv.f * w1;
        cv.u = u1 & 0xffff0000u; ay += cv.f * w1;
        cv.u = u2 << 16;         ax += cv.f * w2;
        cv.u = u2 & 0xffff0000u; ay += cv.f * w2;
        cv.u = u3 << 16;         ax += cv.f * w3;
        cv.u = u3 & 0xffff0000u; ay += cv.f * w3;
    }
    for (; e < m; ++e) {
        int s = __shfl(mysrc, e);
        float w = __shfl(myw, e);
        unsigned int u = h2[(size_t)s * 64 + lane];
        cv.u = u << 16;          ax += cv.f * w;
        cv.u = u & 0xffff0000u;  ay += cv.f * w;
    }
    for (int j = beg + 64; j < end; ++j) {
        int s = csr[j];
        float w = dinv[s] * di;
        unsigned int u = h2[(size_t)s * 64 + lane];
        cv.u = u << 16;          ax += cv.f * w;
        cv.u = u & 0xffff0000u;  ay += cv.f * w;
    }

    float2 bv = ((const float2*)bias)[lane];
    float ox = fmaxf(ax + bv.x, 0.0f);
    float oy = fmaxf(ay + bv.y, 0.0f);
    unsigned int pack = (unsigned int)f2bf(ox) | ((unsigned int)f2bf(oy) << 16);
    ((unsigned int*)out)[(size_t)node * 64 + lane] = pack;
}

// Segmented mean-pool over sorted batch; h is bf16.
#define POOL_CHUNK 64
__global__ __launch_bounds__(128) void k_pool(const unsigned short* __restrict__ h,
                                              const int* __restrict__ batch,
                                              float* __restrict__ sums,
                                              float* __restrict__ cnt, int n) {
    int d = threadIdx.x;
    int c0 = blockIdx.x * POOL_CHUNK;
    if (c0 >= n) return;
    int c1 = min(c0 + POOL_CHUNK, n);
    float acc = 0.f, cc = 0.f;
    int g_cur = batch[c0];
    for (int i = c0; i < c1; ++i) {
        int g = batch[i];
        if (g != g_cur) {
            atomicAdd(&sums[g_cur * 128 + d], acc);
            if (d == 0) atomicAdd(&cnt[g_cur], cc);
            acc = 0.f; cc = 0.f; g_cur = g;
        }
        acc += bf2f(h[(size_t)i * 128 + d]);
        cc += 1.f;
    }
    atomicAdd(&sums[g_cur * 128 + d], acc);
    if (d == 0) atomicAdd(&cnt[g_cur], cc);
}

// One block per graph: pooled mean -> Linear+ReLU -> dot+sigmoid.
__global__ __launch_bounds__(128) void k_head(const float* __restrict__ sums,
                                              const float* __restrict__ cnt,
                                              const float* __restrict__ Wh1,
                                              const float* __restrict__ bh1,
                                              const float* __restrict__ Wh2,
                                              const float* __restrict__ bh2,
                                              float* __restrict__ out) {
    int g = blockIdx.x;
    int d = threadIdx.x;
    __shared__ float sp[128];
    __shared__ float red[128];
    float c = fmaxf(cnt[g], 1.0f);
    sp[d] = sums[g * 128 + d] / c;
    __syncthreads();
    float acc = bh1[d];
    for (int k = 0; k < 128; ++k) acc += sp[k] * Wh1[k * 128 + d];
    float z = fmaxf(acc, 0.f);
    red[d] = z * Wh2[d];
    __syncthreads();
    for (int off = 64; off > 0; off >>= 1) {
        if (d < off) red[d] += red[d + off];
        __syncthreads();
    }
    if (d == 0) out[g] = 1.f / (1.f + expf(-(red[0] + bh2[0])));
}

extern "C" void kernel_launch(void* const* d_in, const int* in_sizes, int n_in,
                              void* d_out, int out_size, void* d_ws,
                              size_t ws_size, hipStream_t stream) {
    const float* x    = (const float*)d_in[0];
    const int*   ei   = (const int*)d_in[1];
    const int*   batch= (const int*)d_in[2];
    const float* W1   = (const float*)d_in[3];
    const float* b1   = (const float*)d_in[4];
    const float* W2   = (const float*)d_in[5];
    const float* b2   = (const float*)d_in[6];
    const float* Wh1  = (const float*)d_in[7];
    const float* bh1  = (const float*)d_in[8];
    const float* Wh2  = (const float*)d_in[9];
    const float* bh2  = (const float*)d_in[10];
    float* out = (float*)d_out;

    const int n  = in_sizes[0] / 128;  // 50000
    const int ne = in_sizes[1] / 2;    // 800000
    const int* src = ei;
    const int* dst = ei + ne;

    char* p = (char*)d_ws;
    int* hist      = (int*)p;  p += (size_t)NB * NBK * 4;
    int* bstart    = (int*)p;  p += 257 * 4;
    int* row_start = (int*)p;  p += (size_t)(n + 1) * 4;
    float* dinv    = (float*)p; p += (size_t)n * 4;
    unsigned int* ebuf = (unsigned int*)p; p += (size_t)ne * 4;
    int* csr       = (int*)p;  p += (size_t)ne * 4;
    p = (char*)(((uintptr_t)p + 15) & ~(uintptr_t)15);
    unsigned short* Wt1 = (unsigned short*)p; p += 128 * 128 * 2;
    unsigned short* Wt2 = (unsigned short*)p; p += 128 * 128 * 2;
    unsigned short* hbf = (unsigned short*)p; p += (size_t)n * 128 * 2;
    unsigned short* abf = (unsigned short*)p; p += (size_t)n * 128 * 2;
    p = (char*)(((uintptr_t)p + 15) & ~(uintptr_t)15);
    float* sums = (float*)p;   p += (size_t)64 * 128 * 4;
    float* cnt  = (float*)p;

    int chunk = (ne + NB - 1) / NB;
    int nb_g = (n + 63) / 64;
    int nb_a = (n + 3) / 4;
    int nb_p = (n + POOL_CHUNK - 1) / POOL_CHUNK;

    // CSR build: histogram -> scan -> bucket scatter -> per-bucket sort
    k_hist<<<NB, 256, 0, stream>>>(dst, hist, sums, cnt, ne, chunk);
    k_scanb<<<1, 256, 0, stream>>>(hist, bstart, row_start, n, ne);
    k_scat<<<NB, 256, 0, stream>>>(src, dst, hist, ebuf, ne, chunk);
    k_bsort<<<256, 256, 0, stream>>>(ebuf, bstart, csr, row_start, dinv, n);

    // weight transpose-casts (both in one launch)
    k_castw<<<128, 256, 0, stream>>>(W1, W2, Wt1, Wt2);

    // conv1 (GEMM reads f32 x directly)
    k_gemm_mfma<true><<<nb_g, 256, 0, stream>>>((const void*)x, (const short*)Wt1, hbf, n);
    k_agg<<<nb_a, 256, 0, stream>>>(hbf, dinv, csr, row_start, b1, abf, n);

    // conv2
    k_gemm_mfma<false><<<nb_g, 256, 0, stream>>>((const void*)abf, (const short*)Wt2, hbf, n);
    k_agg<<<nb_a, 256, 0, stream>>>(hbf, dinv, csr, row_start, b2, abf, n);

    // pool + head
    k_pool<<<nb_p, 128, 0, stream>>>(abf, batch, sums, cnt, n);
    k_head<<<64, 128, 0, stream>>>(sums, cnt, Wh1, bh1, Wh2, bh2, out);
}